// Round 10
// baseline (156.446 us; speedup 1.0000x reference)
//
#include <hip/hip_runtime.h>
#include <hip/hip_bf16.h>
#include <stdint.h>

typedef unsigned short u16;
typedef __bf16 bf16_t;
typedef bf16_t bf16x8 __attribute__((ext_vector_type(8)));
typedef float f32x4 __attribute__((ext_vector_type(4)));

#define NTOK 32768
#define CEMB 256
#define NHEAD 8
#define HD 32
#define BSEG 128
#define TSEG 256

// 1/sqrt(32) * log2(e): folded into Q at projection time.
#define SCQ (0.17677669529663687f * 1.4426950408889634f)

static __device__ __forceinline__ bf16x8 ld16(const u16* p) {
  uint4 v = *reinterpret_cast<const uint4*>(p);
  return __builtin_bit_cast(bf16x8, v);
}
static __device__ __forceinline__ u16 f2b(float f) {
  return __builtin_bit_cast(u16, (bf16_t)f);
}

typedef __attribute__((address_space(1))) const void GASV;
typedef __attribute__((address_space(3))) void LASV;
static __device__ __forceinline__ void stage16(const u16* g, u16* l) {
  __builtin_amdgcn_global_load_lds((GASV*)g, (LASV*)l, 16, 0, 0);
}

// ---------------- K0: convert x and weights to bf16 ----------------
__global__ void k_convert(const float* __restrict__ x,
                          const float* __restrict__ wq, const float* __restrict__ wk,
                          const float* __restrict__ wv, const float* __restrict__ wp,
                          u16* __restrict__ xb, u16* __restrict__ wb) {
  const int XSLOTS = (NTOK * CEMB) / 8;      // 1048576
  const int WSLOTS = (4 * CEMB * CEMB) / 8;  // 32768
  int slot = blockIdx.x * blockDim.x + threadIdx.x;
  if (slot >= XSLOTS + WSLOTS) return;
  const float* src;
  u16* dst;
  if (slot < XSLOTS) {
    src = x + slot * 8;
    dst = xb + slot * 8;
  } else {
    int e = (slot - XSLOTS) * 8;
    int wsel = e >> 16, off = e & 65535;
    const float* s0 = (wsel == 0) ? wq : ((wsel == 1) ? wk : ((wsel == 2) ? wv : wp));
    src = s0 + off;
    dst = wb + e;
  }
  float4 a = reinterpret_cast<const float4*>(src)[0];
  float4 b = reinterpret_cast<const float4*>(src)[1];
  u16 o[8] = {f2b(a.x), f2b(a.y), f2b(a.z), f2b(a.w),
              f2b(b.x), f2b(b.y), f2b(b.z), f2b(b.w)};
  *reinterpret_cast<uint4*>(dst) = *reinterpret_cast<const uint4*>(o);
}

// ======== shared GEMM core pieces (BM=128, BN=128, BK=64, 4 waves 2x2) ========
#define GEMM_MAIN_LOOP(Asrc, Bsrc)                                              \
  f32x4 acc[4][4];                                                              \
  _Pragma("unroll") for (int mf = 0; mf < 4; ++mf)                              \
      _Pragma("unroll") for (int nf = 0; nf < 4; ++nf) {                        \
    f32x4 z = {0.f, 0.f, 0.f, 0.f};                                             \
    acc[mf][nf] = z;                                                            \
  }                                                                             \
  u16* As = lds;                                                                \
  u16* Bs = lds + 16384;                                                        \
  auto STAGE = [&](int buf, int kt) {                                           \
    _Pragma("unroll") for (int i = 0; i < 4; ++i) {                             \
      int cidx = i * 256 + tid;                                                 \
      int row = cidx >> 3;                                                      \
      int scb = ((cidx & 7) << 4) ^ ((row & 7) << 4); /* src col bytes */       \
      u16* dst_lds = As + buf * 8192 + (i * 256 + w * 64) * 8;                  \
      stage16(Asrc + (size_t)(m0 + row) * CEMB + kt * 64 + (scb >> 1), dst_lds);\
      u16* dst_ldsb = Bs + buf * 8192 + (i * 256 + w * 64) * 8;                 \
      stage16(Bsrc + (size_t)(n0 + row) * CEMB + kt * 64 + (scb >> 1), dst_ldsb);\
    }                                                                           \
  };                                                                            \
  STAGE(0, 0);                                                                  \
  __syncthreads();                                                              \
  for (int kt = 0; kt < 4; ++kt) {                                              \
    int buf = kt & 1;                                                           \
    if (kt < 3) STAGE(buf ^ 1, kt + 1);                                         \
    bf16x8 av[4][2], bw[4][2];                                                  \
    _Pragma("unroll") for (int mf = 0; mf < 4; ++mf)                            \
        _Pragma("unroll") for (int kk = 0; kk < 2; ++kk) {                      \
      int row = wr * 64 + mf * 16 + lr;                                         \
      int byte = row * 128 + ((kk * 64 + lg * 16) ^ ((row & 7) << 4));          \
      av[mf][kk] = *reinterpret_cast<const bf16x8*>(                            \
          (const char*)(As + buf * 8192) + byte);                               \
    }                                                                           \
    _Pragma("unroll") for (int nf = 0; nf < 4; ++nf)                            \
        _Pragma("unroll") for (int kk = 0; kk < 2; ++kk) {                      \
      int row = wc * 64 + nf * 16 + lr;                                         \
      int byte = row * 128 + ((kk * 64 + lg * 16) ^ ((row & 7) << 4));          \
      bw[nf][kk] = *reinterpret_cast<const bf16x8*>(                            \
          (const char*)(Bs + buf * 8192) + byte);                               \
    }                                                                           \
    _Pragma("unroll") for (int kk = 0; kk < 2; ++kk)                            \
        _Pragma("unroll") for (int nf = 0; nf < 4; ++nf)                        \
            _Pragma("unroll") for (int mf = 0; mf < 4; ++mf)                    \
      acc[mf][nf] = __builtin_amdgcn_mfma_f32_16x16x32_bf16(                    \
          av[mf][kk], bw[nf][kk], acc[mf][nf], 0, 0, 0);                        \
    __syncthreads();                                                            \
  }

// ---------------- K1: QKV projection GEMMs ----------------
// Q output is pre-scaled by SCQ so k_attn's QK^T feeds exp2 directly.
__global__ __launch_bounds__(256, 2)
void k_qkv(const u16* __restrict__ xb, const u16* __restrict__ wb,
           const float* __restrict__ bq, const float* __restrict__ bk,
           const float* __restrict__ bv,
           u16* __restrict__ q_ws, u16* __restrict__ k_ws, u16* __restrict__ v_ws) {
  const int d = blockIdx.x;
  const int xcd = d & 7, i = d >> 3;          // i in 0..191
  const int m_idx = xcd * 32 + i / 6;         // 0..255
  const int rr = i % 6;
  const int mode = rr >> 1;                   // 0=Q,1=K,2=V
  const int n0 = (rr & 1) * 128;
  const int m0 = m_idx * 128;
  const int tid = threadIdx.x;
  const int w = tid >> 6, l = tid & 63;
  const int lr = l & 15, lg = l >> 4;
  const int wr = w >> 1, wc = w & 1;

  __shared__ u16 lds[32768];  // 64 KB

  const u16* W = wb + mode * (CEMB * CEMB);
  const float* bias = (mode == 0) ? bq : ((mode == 1) ? bk : bv);

  GEMM_MAIN_LOOP(xb, W)

  float bb[4];
#pragma unroll
  for (int nf = 0; nf < 4; ++nf) bb[nf] = bias[n0 + wc * 64 + nf * 16 + lr];

  const float osc = (mode == 0) ? SCQ : 1.0f;

  if (mode < 2) {
    // bounce via LDS -> plain [m][256] bf16 layout, coalesced 16B stores
    u16* Et = lds;
#pragma unroll
    for (int mf = 0; mf < 4; ++mf)
#pragma unroll
      for (int nf = 0; nf < 4; ++nf)
#pragma unroll
        for (int r = 0; r < 4; ++r) {
          int row = wr * 64 + mf * 16 + lg * 4 + r;
          int col = wc * 64 + nf * 16 + lr;
          int byte = (row * 256 + col * 2) ^ ((row & 7) << 4);
          *(u16*)((char*)Et + byte) = f2b((acc[mf][nf][r] + bb[nf]) * osc);
        }
    __syncthreads();
    u16* out = (mode == 0) ? q_ws : k_ws;
    int row_l = tid >> 1, half = tid & 1;
    u16* dstp = out + (size_t)(m0 + row_l) * CEMB + n0 + half * 64;
#pragma unroll
    for (int j = 0; j < 8; ++j) {
      int byte = row_l * 256 + (((half * 64 + j * 8) * 2) ^ ((row_l & 7) << 4));
      *reinterpret_cast<uint4*>(dstp + j * 8) =
          *reinterpret_cast<const uint4*>((const char*)Et + byte);
    }
  } else {
    // V: bounce transposed -> v_ws[b,h,d,t], coalesced 16B stores
    u16* Vt = lds;
#pragma unroll
    for (int mf = 0; mf < 4; ++mf)
#pragma unroll
      for (int nf = 0; nf < 4; ++nf)
#pragma unroll
        for (int r = 0; r < 4; ++r) {
          int row = wr * 64 + mf * 16 + lg * 4 + r;
          int col = wc * 64 + nf * 16 + lr;
          int byte = (col * 256 + row * 2) ^ ((col & 7) << 4);
          *(u16*)((char*)Vt + byte) = f2b(acc[mf][nf][r] + bb[nf]);
        }
    __syncthreads();
    int col_l = tid >> 1, half = tid & 1;
    int c = n0 + col_l, hh = c >> 5, dd = c & 31;
    int bs = m0 >> 8, t0 = m0 & 255;
    u16* dst = v_ws + ((size_t)(bs * NHEAD + hh) * HD + dd) * TSEG + t0 + half * 64;
#pragma unroll
    for (int j = 0; j < 8; ++j) {
      int byte = col_l * 256 + ((half * 128 + j * 16) ^ ((col_l & 7) << 4));
      *reinterpret_cast<uint4*>(dst + j * 8) =
          *reinterpret_cast<const uint4*>((const char*)Vt + byte);
    }
  }
}

// ---------------- K2: attention ----------------
// Block = (b, t-half), 1024 threads = 16 waves = 2 head-groups x 8 t-tiles.
// Wave (hg, wt): t rows [th*128+wt*16, +16), heads hg*4..hg*4+3 serial.
// Per-hg LDS staging (R8's scheme, duplicated per hg): each hg's 512
// threads stage their own head stream, double-buffered via global_load_lds.
// 128 KB dynamic LDS -> 1 block/CU, 16 waves/CU (50% occ). Each head staged
// exactly once per block -> FETCH unchanged (~27 MB).
// Head-mean: cross-hg chunked LDS combine (R6's proven epilogue).
__global__ __launch_bounds__(1024, 4)
void k_attn(const u16* __restrict__ q_ws, const u16* __restrict__ k_ws,
            const u16* __restrict__ v_ws,
            u16* __restrict__ y_ws, float* __restrict__ mean_out) {
  const int dblk = blockIdx.x;
  const int xcd = dblk & 7, ii = dblk >> 3;  // ii in 0..31
  const int b = xcd * 16 + (ii >> 1);
  const int th = ii & 1;
  const int tid = threadIdx.x;
  const int w = tid >> 6, l = tid & 63;
  const int lr = l & 15, lg = l >> 4;
  const int hg = w >> 3, wt = w & 7;
  const int tbase = th * 128 + wt * 16;

  // K[hg][buf][8192 u16] at 0 (64 KB) ; V[hg][buf][8192 u16] at 32768 (64 KB)
  extern __shared__ u16 ldsKV[];

  float macc[16][4];
#pragma unroll
  for (int st = 0; st < 16; ++st)
#pragma unroll
    for (int r = 0; r < 4; ++r) macc[st][r] = 0.f;

  const u16* qseg = q_ws + (size_t)b * TSEG * CEMB;
  const u16* kseg = k_ws + (size_t)b * TSEG * CEMB;
  const u16* vseg = v_ws + (size_t)(b * NHEAD) * HD * TSEG;

  // stage this thread's hg's head (hg*4+step) into buffer bn
  auto STAGE_KV = [&](int step, int bn) {
    const int hn = hg * 4 + step;
    u16* Kb = ldsKV + (hg * 2 + bn) * 8192;
    u16* Vb = ldsKV + 32768 + (hg * 2 + bn) * 8192;
    const int tl = tid & 511;
#pragma unroll
    for (int r = 0; r < 2; ++r) {
      int idx = r * 512 + tl;              // 0..1023 chunk id
      int c = idx >> 6, l2 = idx & 63;     // frag, lane
      int lr2 = l2 & 15, lg2 = l2 >> 4;
      int srow = 32 * (c >> 1) + 4 * (c & 1) + 8 * (lr2 >> 2) + (lr2 & 3);
      stage16(kseg + srow * CEMB + hn * HD + lg2 * 8, Kb + idx * 8);
      int vrow = (c >> 3) * 16 + lr2;
      int vcol = (c & 7) * 32 + lg2 * 8;
      stage16(vseg + (size_t)(hn * HD + vrow) * TSEG + vcol, Vb + idx * 8);
    }
  };

  STAGE_KV(0, 0);
  bf16x8 qf = ld16(qseg + (tbase + lr) * CEMB + (hg * 4) * HD + lg * 8);

  for (int i = 0; i < 4; ++i) {
    const int bn = i & 1;
    const int h = hg * 4 + i;
    __syncthreads();  // vmcnt(0) drain (stage i + qf) + barrier
    if (i < 3) STAGE_KV(i + 1, bn ^ 1);
    const u16* Kb = ldsKV + (hg * 2 + bn) * 8192;
    const u16* Vb = ldsKV + 32768 + (hg * 2 + bn) * 8192;

    // S^T = mfma(K, Q); Q pre-scaled, so s is the exp2 argument directly
    float s[16][4];
#pragma unroll
    for (int st = 0; st < 16; ++st) {
      bf16x8 kf = *reinterpret_cast<const bf16x8*>(Kb + (st * 64 + l) * 8);
      f32x4 z = {0.f, 0.f, 0.f, 0.f};
      f32x4 dd = __builtin_amdgcn_mfma_f32_16x16x32_bf16(kf, qf, z, 0, 0, 0);
#pragma unroll
      for (int r = 0; r < 4; ++r) s[st][r] = dd[r];
    }

    // prefetch Q for next head (drained at next __syncthreads)
    qf = ld16(qseg + (tbase + lr) * CEMB + (hg * 4 + ((i + 1) & 3)) * HD + lg * 8);

    // row max: 4 parallel 16-deep chains + tree combine + 2 shfl
    float m0x = s[0][0], m1x = s[0][1], m2x = s[0][2], m3x = s[0][3];
#pragma unroll
    for (int st = 1; st < 16; ++st) {
      m0x = fmaxf(m0x, s[st][0]);
      m1x = fmaxf(m1x, s[st][1]);
      m2x = fmaxf(m2x, s[st][2]);
      m3x = fmaxf(m3x, s[st][3]);
    }
    float mx = fmaxf(fmaxf(m0x, m1x), fmaxf(m2x, m3x));
    mx = fmaxf(mx, __shfl_xor(mx, 16, 64));
    mx = fmaxf(mx, __shfl_xor(mx, 32, 64));

    // exp2 + 4-way parallel sum
    float s0 = 0.f, s1 = 0.f, s2 = 0.f, s3 = 0.f;
#pragma unroll
    for (int st = 0; st < 16; ++st) {
      float p0 = exp2f(s[st][0] - mx);
      float p1 = exp2f(s[st][1] - mx);
      float p2 = exp2f(s[st][2] - mx);
      float p3 = exp2f(s[st][3] - mx);
      s[st][0] = p0; s[st][1] = p1; s[st][2] = p2; s[st][3] = p3;
      s0 += p0; s1 += p1; s2 += p2; s3 += p3;
    }
    float sm = (s0 + s1) + (s2 + s3);
    sm += __shfl_xor(sm, 16, 64);
    sm += __shfl_xor(sm, 32, 64);
    float inv = __builtin_amdgcn_rcpf(sm);

    // pack RAW p (<=1) for PV; macc accumulates normalized p via fma
    bf16x8 pb[8];
#pragma unroll
    for (int kk = 0; kk < 8; ++kk)
#pragma unroll
      for (int e = 0; e < 4; ++e) {
        float p0 = s[2 * kk][e];
        float p1 = s[2 * kk + 1][e];
        macc[2 * kk][e] = fmaf(p0, inv, macc[2 * kk][e]);
        macc[2 * kk + 1][e] = fmaf(p1, inv, macc[2 * kk + 1][e]);
        pb[kk][e] = (bf16_t)p0;
        pb[kk][4 + e] = (bf16_t)p1;
      }

    // PV on raw P; normalize y by inv afterwards
#pragma unroll
    for (int dt = 0; dt < 2; ++dt) {
      f32x4 y = {0.f, 0.f, 0.f, 0.f};
#pragma unroll
      for (int kk = 0; kk < 8; ++kk) {
        bf16x8 vf = *reinterpret_cast<const bf16x8*>(Vb + ((dt * 8 + kk) * 64 + l) * 8);
        y = __builtin_amdgcn_mfma_f32_16x16x32_bf16(vf, pb[kk], y, 0, 0, 0);
      }
      u16 o[4] = {f2b(y[0] * inv), f2b(y[1] * inv), f2b(y[2] * inv), f2b(y[3] * inv)};
      *reinterpret_cast<uint2*>(
          y_ws + (size_t)(b * TSEG + tbase + lr) * CEMB + h * HD + dt * 16 + lg * 4) =
          *reinterpret_cast<const uint2*>(o);
    }
  }

  __syncthreads();  // protect KV buffers before reuse as mean staging

  // ---- head-mean combine across hgs: 8 s-chunks of 32 (R6 epilogue) ----
  float* smem = reinterpret_cast<float*>(ldsKV);   // [2hg][8wt][16t][33s] f32
  float* smw = smem + (((hg * 8 + wt) * 16) + lr) * 33;
  const int wt_r = w & 7, rhalf = w >> 3;
  const int row = rhalf * 8 + (l >> 3);
  const int col = (l & 7) * 4;
  const float* rd0 = smem + (((0 * 8 + wt_r) * 16) + row) * 33 + col;
  const float* rd1 = smem + (((1 * 8 + wt_r) * 16) + row) * 33 + col;
  float* gdst = mean_out + (size_t)(b * TSEG + th * 128 + wt_r * 16 + row) * TSEG + col;

  for (int c = 0; c < 8; ++c) {
#pragma unroll
    for (int j = 0; j < 2; ++j)
#pragma unroll
      for (int r = 0; r < 4; ++r)
        smw[4 * j + 8 * lg + r] = macc[2 * c + j][r];
    __syncthreads();
    f32x4 a = *reinterpret_cast<const f32x4*>(rd0);
    f32x4 bb = *reinterpret_cast<const f32x4*>(rd1);
    f32x4 o;
#pragma unroll
    for (int e = 0; e < 4; ++e) o[e] = (a[e] + bb[e]) * 0.125f;
    *reinterpret_cast<f32x4*>(gdst + c * 32) = o;
    if (c < 7) __syncthreads();
  }
}

// ---------------- K3: output projection ----------------
__global__ __launch_bounds__(256, 2)
void k_proj(const u16* __restrict__ yb, const u16* __restrict__ wb,
            const float* __restrict__ bp, float* __restrict__ out) {
  const int d = blockIdx.x;
  const int xcd = d & 7, i = d >> 3;          // i in 0..63
  const int m0 = (xcd * 32 + (i >> 1)) * 128;
  const int n0 = (i & 1) * 128;
  const int tid = threadIdx.x;
  const int w = tid >> 6, l = tid & 63;
  const int lr = l & 15, lg = l >> 4;
  const int wr = w >> 1, wc = w & 1;
  const u16* W = wb + 3 * (CEMB * CEMB);

  __shared__ u16 lds[32768];  // 64 KB

  GEMM_MAIN_LOOP(yb, W)

  float bb[4];
#pragma unroll
  for (int nf = 0; nf < 4; ++nf) bb[nf] = bp[n0 + wc * 64 + nf * 16 + lr];
#pragma unroll
  for (int mf = 0; mf < 4; ++mf)
#pragma unroll
    for (int nf = 0; nf < 4; ++nf)
#pragma unroll
      for (int r = 0; r < 4; ++r) {
        int m = m0 + wr * 64 + mf * 16 + lg * 4 + r;
        int c = n0 + wc * 64 + nf * 16 + lr;
        out[(size_t)m * CEMB + c] = acc[mf][nf][r] + bb[nf];
      }
}

extern "C" void kernel_launch(void* const* d_in, const int* in_sizes, int n_in,
                              void* d_out, int out_size, void* d_ws, size_t ws_size,
                              hipStream_t stream) {
  (void)in_sizes; (void)n_in; (void)out_size; (void)ws_size;
  const float* x  = (const float*)d_in[0];
  // d_in[1] = batch indices (unused: equal-length segments, B=128, T=256)
  const float* Wq = (const float*)d_in[2];
  const float* bq = (const float*)d_in[3];
  const float* Wk = (const float*)d_in[4];
  const float* bk = (const float*)d_in[5];
  const float* Wv = (const float*)d_in[6];
  const float* bv = (const float*)d_in[7];
  const float* Wp = (const float*)d_in[8];
  const float* bp = (const float*)d_in[9];
  float* out = (float*)d_out;

  char* ws = (char*)d_ws;
  u16* xb   = (u16*)(ws);                    // 16 MiB (reused as y_ws after k_qkv)
  u16* wb   = (u16*)(ws + 16777216);         // 512 KiB
  u16* q_ws = (u16*)(ws + 17301504);         // 16 MiB, plain [m][256], pre-scaled
  u16* k_ws = (u16*)(ws + 34078720);         // 16 MiB, plain [m][256]
  u16* v_ws = (u16*)(ws + 50855936);         // 16 MiB, transposed [b,h,d,t]
  u16* y_ws = xb;
  float* mean_out = out + (size_t)NTOK * CEMB;

  k_convert<<<4224, 256, 0, stream>>>(x, Wq, Wk, Wv, Wp, xb, wb);
  k_qkv<<<1536, 256, 0, stream>>>(xb, wb, bq, bk, bv, q_ws, k_ws, v_ws);
  k_attn<<<256, 1024, 131072, stream>>>(q_ws, k_ws, v_ws, y_ws, mean_out);
  k_proj<<<512, 256, 0, stream>>>(y_ws, wb, bp, out);
}

// Round 11
// 99.250 us; speedup vs baseline: 1.5763x; 1.5763x over previous
//
#include <hip/hip_runtime.h>
#include <hip/hip_bf16.h>
#include <stdint.h>

typedef unsigned short u16;
typedef __bf16 bf16_t;
typedef bf16_t bf16x8 __attribute__((ext_vector_type(8)));
typedef float f32x4 __attribute__((ext_vector_type(4)));

#define NTOK 32768
#define CEMB 256
#define NHEAD 8
#define HD 32
#define BSEG 128
#define TSEG 256

// 1/sqrt(32) * log2(e): folded into Q at projection time.
#define SCQ (0.17677669529663687f * 1.4426950408889634f)

static __device__ __forceinline__ bf16x8 ld16(const u16* p) {
  uint4 v = *reinterpret_cast<const uint4*>(p);
  return __builtin_bit_cast(bf16x8, v);
}
static __device__ __forceinline__ u16 f2b(float f) {
  return __builtin_bit_cast(u16, (bf16_t)f);
}

typedef __attribute__((address_space(1))) const void GASV;
typedef __attribute__((address_space(3))) void LASV;
static __device__ __forceinline__ void stage16(const u16* g, u16* l) {
  __builtin_amdgcn_global_load_lds((GASV*)g, (LASV*)l, 16, 0, 0);
}

// ---------------- K0: convert x and weights to bf16 ----------------
__global__ void k_convert(const float* __restrict__ x,
                          const float* __restrict__ wq, const float* __restrict__ wk,
                          const float* __restrict__ wv, const float* __restrict__ wp,
                          u16* __restrict__ xb, u16* __restrict__ wb) {
  const int XSLOTS = (NTOK * CEMB) / 8;      // 1048576
  const int WSLOTS = (4 * CEMB * CEMB) / 8;  // 32768
  int slot = blockIdx.x * blockDim.x + threadIdx.x;
  if (slot >= XSLOTS + WSLOTS) return;
  const float* src;
  u16* dst;
  if (slot < XSLOTS) {
    src = x + slot * 8;
    dst = xb + slot * 8;
  } else {
    int e = (slot - XSLOTS) * 8;
    int wsel = e >> 16, off = e & 65535;
    const float* s0 = (wsel == 0) ? wq : ((wsel == 1) ? wk : ((wsel == 2) ? wv : wp));
    src = s0 + off;
    dst = wb + e;
  }
  float4 a = reinterpret_cast<const float4*>(src)[0];
  float4 b = reinterpret_cast<const float4*>(src)[1];
  u16 o[8] = {f2b(a.x), f2b(a.y), f2b(a.z), f2b(a.w),
              f2b(b.x), f2b(b.y), f2b(b.z), f2b(b.w)};
  *reinterpret_cast<uint4*>(dst) = *reinterpret_cast<const uint4*>(o);
}

// ======== shared GEMM core pieces (BM=128, BN=128, BK=64, 4 waves 2x2) ========
#define GEMM_MAIN_LOOP(Asrc, Bsrc)                                              \
  f32x4 acc[4][4];                                                              \
  _Pragma("unroll") for (int mf = 0; mf < 4; ++mf)                              \
      _Pragma("unroll") for (int nf = 0; nf < 4; ++nf) {                        \
    f32x4 z = {0.f, 0.f, 0.f, 0.f};                                             \
    acc[mf][nf] = z;                                                            \
  }                                                                             \
  u16* As = lds;                                                                \
  u16* Bs = lds + 16384;                                                        \
  auto STAGE = [&](int buf, int kt) {                                           \
    _Pragma("unroll") for (int i = 0; i < 4; ++i) {                             \
      int cidx = i * 256 + tid;                                                 \
      int row = cidx >> 3;                                                      \
      int scb = ((cidx & 7) << 4) ^ ((row & 7) << 4); /* src col bytes */       \
      u16* dst_lds = As + buf * 8192 + (i * 256 + w * 64) * 8;                  \
      stage16(Asrc + (size_t)(m0 + row) * CEMB + kt * 64 + (scb >> 1), dst_lds);\
      u16* dst_ldsb = Bs + buf * 8192 + (i * 256 + w * 64) * 8;                 \
      stage16(Bsrc + (size_t)(n0 + row) * CEMB + kt * 64 + (scb >> 1), dst_ldsb);\
    }                                                                           \
  };                                                                            \
  STAGE(0, 0);                                                                  \
  __syncthreads();                                                              \
  for (int kt = 0; kt < 4; ++kt) {                                              \
    int buf = kt & 1;                                                           \
    if (kt < 3) STAGE(buf ^ 1, kt + 1);                                         \
    bf16x8 av[4][2], bw[4][2];                                                  \
    _Pragma("unroll") for (int mf = 0; mf < 4; ++mf)                            \
        _Pragma("unroll") for (int kk = 0; kk < 2; ++kk) {                      \
      int row = wr * 64 + mf * 16 + lr;                                         \
      int byte = row * 128 + ((kk * 64 + lg * 16) ^ ((row & 7) << 4));          \
      av[mf][kk] = *reinterpret_cast<const bf16x8*>(                            \
          (const char*)(As + buf * 8192) + byte);                               \
    }                                                                           \
    _Pragma("unroll") for (int nf = 0; nf < 4; ++nf)                            \
        _Pragma("unroll") for (int kk = 0; kk < 2; ++kk) {                      \
      int row = wc * 64 + nf * 16 + lr;                                         \
      int byte = row * 128 + ((kk * 64 + lg * 16) ^ ((row & 7) << 4));          \
      bw[nf][kk] = *reinterpret_cast<const bf16x8*>(                            \
          (const char*)(Bs + buf * 8192) + byte);                               \
    }                                                                           \
    _Pragma("unroll") for (int kk = 0; kk < 2; ++kk)                            \
        _Pragma("unroll") for (int nf = 0; nf < 4; ++nf)                        \
            _Pragma("unroll") for (int mf = 0; mf < 4; ++mf)                    \
      acc[mf][nf] = __builtin_amdgcn_mfma_f32_16x16x32_bf16(                    \
          av[mf][kk], bw[nf][kk], acc[mf][nf], 0, 0, 0);                        \
    __syncthreads();                                                            \
  }

// ---------------- K1: QKV projection GEMMs ----------------
// Q output is pre-scaled by SCQ so k_attn's QK^T feeds exp2 directly.
__global__ __launch_bounds__(256, 2)
void k_qkv(const u16* __restrict__ xb, const u16* __restrict__ wb,
           const float* __restrict__ bq, const float* __restrict__ bk,
           const float* __restrict__ bv,
           u16* __restrict__ q_ws, u16* __restrict__ k_ws, u16* __restrict__ v_ws) {
  const int d = blockIdx.x;
  const int xcd = d & 7, i = d >> 3;          // i in 0..191
  const int m_idx = xcd * 32 + i / 6;         // 0..255
  const int rr = i % 6;
  const int mode = rr >> 1;                   // 0=Q,1=K,2=V
  const int n0 = (rr & 1) * 128;
  const int m0 = m_idx * 128;
  const int tid = threadIdx.x;
  const int w = tid >> 6, l = tid & 63;
  const int lr = l & 15, lg = l >> 4;
  const int wr = w >> 1, wc = w & 1;

  __shared__ u16 lds[32768];  // 64 KB

  const u16* W = wb + mode * (CEMB * CEMB);
  const float* bias = (mode == 0) ? bq : ((mode == 1) ? bk : bv);

  GEMM_MAIN_LOOP(xb, W)

  float bb[4];
#pragma unroll
  for (int nf = 0; nf < 4; ++nf) bb[nf] = bias[n0 + wc * 64 + nf * 16 + lr];

  const float osc = (mode == 0) ? SCQ : 1.0f;

  if (mode < 2) {
    // bounce via LDS -> plain [m][256] bf16 layout, coalesced 16B stores
    u16* Et = lds;
#pragma unroll
    for (int mf = 0; mf < 4; ++mf)
#pragma unroll
      for (int nf = 0; nf < 4; ++nf)
#pragma unroll
        for (int r = 0; r < 4; ++r) {
          int row = wr * 64 + mf * 16 + lg * 4 + r;
          int col = wc * 64 + nf * 16 + lr;
          int byte = (row * 256 + col * 2) ^ ((row & 7) << 4);
          *(u16*)((char*)Et + byte) = f2b((acc[mf][nf][r] + bb[nf]) * osc);
        }
    __syncthreads();
    u16* out = (mode == 0) ? q_ws : k_ws;
    int row_l = tid >> 1, half = tid & 1;
    u16* dstp = out + (size_t)(m0 + row_l) * CEMB + n0 + half * 64;
#pragma unroll
    for (int j = 0; j < 8; ++j) {
      int byte = row_l * 256 + (((half * 64 + j * 8) * 2) ^ ((row_l & 7) << 4));
      *reinterpret_cast<uint4*>(dstp + j * 8) =
          *reinterpret_cast<const uint4*>((const char*)Et + byte);
    }
  } else {
    // V: bounce transposed -> v_ws[b,h,d,t], coalesced 16B stores
    u16* Vt = lds;
#pragma unroll
    for (int mf = 0; mf < 4; ++mf)
#pragma unroll
      for (int nf = 0; nf < 4; ++nf)
#pragma unroll
        for (int r = 0; r < 4; ++r) {
          int row = wr * 64 + mf * 16 + lg * 4 + r;
          int col = wc * 64 + nf * 16 + lr;
          int byte = (col * 256 + row * 2) ^ ((col & 7) << 4);
          *(u16*)((char*)Vt + byte) = f2b(acc[mf][nf][r] + bb[nf]);
        }
    __syncthreads();
    int col_l = tid >> 1, half = tid & 1;
    int c = n0 + col_l, hh = c >> 5, dd = c & 31;
    int bs = m0 >> 8, t0 = m0 & 255;
    u16* dst = v_ws + ((size_t)(bs * NHEAD + hh) * HD + dd) * TSEG + t0 + half * 64;
#pragma unroll
    for (int j = 0; j < 8; ++j) {
      int byte = col_l * 256 + ((half * 128 + j * 16) ^ ((col_l & 7) << 4));
      *reinterpret_cast<uint4*>(dst + j * 8) =
          *reinterpret_cast<const uint4*>((const char*)Vt + byte);
    }
  }
}

// ---------------- K2: attention ----------------
// R9 fetch-clean structure (256 blocks = (b,t-half), 8 waves, sequential
// sweep) + HEAD-PAIR ILP: each wave processes heads 2i,2i+1 concurrently
// (independent register streams -> dual dependency chains fill the SIMD).
// Pair staging reads full 128B lines (heads 2i/2i+1 adjacent columns).
// No-max softmax: |s| <= ~4 << 126, exp2 directly (saves max-reduce and
// shortens the critical path). LDS 128KB dynamic: K[2buf][2hs][16KB] +
// V[2buf][2hs][16KB].
__global__ __launch_bounds__(512, 2)
void k_attn(const u16* __restrict__ q_ws, const u16* __restrict__ k_ws,
            const u16* __restrict__ v_ws,
            u16* __restrict__ y_ws, float* __restrict__ mean_out) {
  const int dblk = blockIdx.x;
  const int xcd = dblk & 7, ii = dblk >> 3;  // ii in 0..31
  const int b = xcd * 16 + (ii >> 1);
  const int th = ii & 1;
  const int tid = threadIdx.x;
  const int w = tid >> 6, l = tid & 63;
  const int lr = l & 15, lg = l >> 4;
  const int tbase = th * 128 + w * 16;

  extern __shared__ u16 ldsKV[];  // K: [(pb*2+hs)][1024ch][8u16] 64KB; V at +32768

  float macc[16][4];
#pragma unroll
  for (int st = 0; st < 16; ++st)
#pragma unroll
    for (int r = 0; r < 4; ++r) macc[st][r] = 0.f;

  const u16* qseg = q_ws + (size_t)b * TSEG * CEMB;
  const u16* kseg = k_ws + (size_t)b * TSEG * CEMB;
  const u16* vseg = v_ws + (size_t)(b * NHEAD) * HD * TSEG;

  // stage K+V for head pair pi (heads 2pi, 2pi+1) into pair-slot pbuf
  auto STAGE_PAIR = [&](int pi, int pbuf) {
#pragma unroll
    for (int r = 0; r < 4; ++r) {
      int idx = r * 512 + tid;             // 0..2047
      int hs = idx >> 10;                  // head-in-pair
      int c = (idx >> 6) & 15;             // frag
      int l2 = idx & 63;
      int lr2 = l2 & 15, lg2 = l2 >> 4;
      int hn = pi * 2 + hs;
      int srow = 32 * (c >> 1) + 4 * (c & 1) + 8 * (lr2 >> 2) + (lr2 & 3);
      stage16(kseg + srow * CEMB + hn * HD + lg2 * 8,
              ldsKV + ((pbuf * 2 + hs) * 1024 + c * 64 + l2) * 8);
      int vrow = (c >> 3) * 16 + lr2;
      int vcol = (c & 7) * 32 + lg2 * 8;
      stage16(vseg + (size_t)(hn * HD + vrow) * TSEG + vcol,
              ldsKV + 32768 + ((pbuf * 2 + hs) * 1024 + c * 64 + l2) * 8);
    }
  };

  STAGE_PAIR(0, 0);
  bf16x8 qa = ld16(qseg + (tbase + lr) * CEMB + 0 * HD + lg * 8);
  bf16x8 qb = ld16(qseg + (tbase + lr) * CEMB + 1 * HD + lg * 8);

  for (int i = 0; i < 4; ++i) {
    const int pbuf = i & 1;
    __syncthreads();  // drains stage(i)+Q vmcnt; protects pbuf^1 for overwrite
    if (i < 3) STAGE_PAIR(i + 1, pbuf ^ 1);
    const u16* KbA = ldsKV + (pbuf * 2 + 0) * 8192;
    const u16* KbB = ldsKV + (pbuf * 2 + 1) * 8192;
    const u16* VbA = ldsKV + 32768 + (pbuf * 2 + 0) * 8192;
    const u16* VbB = ldsKV + 32768 + (pbuf * 2 + 1) * 8192;

    // dual QK^T streams (independent MFMA chains interleave)
    float sA[16][4], sB[16][4];
#pragma unroll
    for (int st = 0; st < 16; ++st) {
      bf16x8 kfA = *reinterpret_cast<const bf16x8*>(KbA + (st * 64 + l) * 8);
      bf16x8 kfB = *reinterpret_cast<const bf16x8*>(KbB + (st * 64 + l) * 8);
      f32x4 z = {0.f, 0.f, 0.f, 0.f};
      f32x4 dA = __builtin_amdgcn_mfma_f32_16x16x32_bf16(kfA, qa, z, 0, 0, 0);
      f32x4 dB = __builtin_amdgcn_mfma_f32_16x16x32_bf16(kfB, qb, z, 0, 0, 0);
#pragma unroll
      for (int r = 0; r < 4; ++r) { sA[st][r] = dA[r]; sB[st][r] = dB[r]; }
    }

    // prefetch Q for next pair
    {
      const int hn0 = ((i + 1) & 3) * 2;
      qa = ld16(qseg + (tbase + lr) * CEMB + hn0 * HD + lg * 8);
      qb = ld16(qseg + (tbase + lr) * CEMB + (hn0 + 1) * HD + lg * 8);
    }

    // no-max exp2 + 4-way parallel sums, both heads (dual chains)
    float a0 = 0.f, a1 = 0.f, a2 = 0.f, a3 = 0.f;
    float b0 = 0.f, b1 = 0.f, b2 = 0.f, b3 = 0.f;
#pragma unroll
    for (int st = 0; st < 16; ++st) {
      float pa0 = exp2f(sA[st][0]), pa1 = exp2f(sA[st][1]);
      float pa2 = exp2f(sA[st][2]), pa3 = exp2f(sA[st][3]);
      float pb0 = exp2f(sB[st][0]), pb1 = exp2f(sB[st][1]);
      float pb2 = exp2f(sB[st][2]), pb3 = exp2f(sB[st][3]);
      sA[st][0] = pa0; sA[st][1] = pa1; sA[st][2] = pa2; sA[st][3] = pa3;
      sB[st][0] = pb0; sB[st][1] = pb1; sB[st][2] = pb2; sB[st][3] = pb3;
      a0 += pa0; a1 += pa1; a2 += pa2; a3 += pa3;
      b0 += pb0; b1 += pb1; b2 += pb2; b3 += pb3;
    }
    float smA = (a0 + a1) + (a2 + a3);
    float smB = (b0 + b1) + (b2 + b3);
    smA += __shfl_xor(smA, 16, 64);
    smB += __shfl_xor(smB, 16, 64);
    smA += __shfl_xor(smA, 32, 64);
    smB += __shfl_xor(smB, 32, 64);
    const float invA = __builtin_amdgcn_rcpf(smA);
    const float invB = __builtin_amdgcn_rcpf(smB);

    // ---- head A: pack raw p, macc fma, PV, y write (sA dies here) ----
    {
      bf16x8 pb[8];
#pragma unroll
      for (int kk = 0; kk < 8; ++kk)
#pragma unroll
        for (int e = 0; e < 4; ++e) {
          float p0 = sA[2 * kk][e];
          float p1 = sA[2 * kk + 1][e];
          macc[2 * kk][e] = fmaf(p0, invA, macc[2 * kk][e]);
          macc[2 * kk + 1][e] = fmaf(p1, invA, macc[2 * kk + 1][e]);
          pb[kk][e] = (bf16_t)p0;
          pb[kk][4 + e] = (bf16_t)p1;
        }
#pragma unroll
      for (int dt = 0; dt < 2; ++dt) {
        f32x4 y = {0.f, 0.f, 0.f, 0.f};
#pragma unroll
        for (int kk = 0; kk < 8; ++kk) {
          bf16x8 vf = *reinterpret_cast<const bf16x8*>(VbA + ((dt * 8 + kk) * 64 + l) * 8);
          y = __builtin_amdgcn_mfma_f32_16x16x32_bf16(vf, pb[kk], y, 0, 0, 0);
        }
        u16 o[4] = {f2b(y[0] * invA), f2b(y[1] * invA), f2b(y[2] * invA), f2b(y[3] * invA)};
        *reinterpret_cast<uint2*>(
            y_ws + (size_t)(b * TSEG + tbase + lr) * CEMB + (2 * i) * HD + dt * 16 + lg * 4) =
            *reinterpret_cast<const uint2*>(o);
      }
    }
    // ---- head B ----
    {
      bf16x8 pb[8];
#pragma unroll
      for (int kk = 0; kk < 8; ++kk)
#pragma unroll
        for (int e = 0; e < 4; ++e) {
          float p0 = sB[2 * kk][e];
          float p1 = sB[2 * kk + 1][e];
          macc[2 * kk][e] = fmaf(p0, invB, macc[2 * kk][e]);
          macc[2 * kk + 1][e] = fmaf(p1, invB, macc[2 * kk + 1][e]);
          pb[kk][e] = (bf16_t)p0;
          pb[kk][4 + e] = (bf16_t)p1;
        }
#pragma unroll
      for (int dt = 0; dt < 2; ++dt) {
        f32x4 y = {0.f, 0.f, 0.f, 0.f};
#pragma unroll
        for (int kk = 0; kk < 8; ++kk) {
          bf16x8 vf = *reinterpret_cast<const bf16x8*>(VbB + ((dt * 8 + kk) * 64 + l) * 8);
          y = __builtin_amdgcn_mfma_f32_16x16x32_bf16(vf, pb[kk], y, 0, 0, 0);
        }
        u16 o[4] = {f2b(y[0] * invB), f2b(y[1] * invB), f2b(y[2] * invB), f2b(y[3] * invB)};
        *reinterpret_cast<uint2*>(
            y_ws + (size_t)(b * TSEG + tbase + lr) * CEMB + (2 * i + 1) * HD + dt * 16 + lg * 4) =
            *reinterpret_cast<const uint2*>(o);
      }
    }
  }

  __syncthreads();  // protect KV buffers before reuse as mean staging

  // head-mean epilogue: 4 s-chunks of 64, wave-private staging (no barriers).
  float* smem = reinterpret_cast<float*>(ldsKV);
  float* smw = smem + w * (16 * 65) + lr * 65;
  const int trow = l >> 2;
  const int cql = (l & 3) * 4;
  const float* srcp = smem + w * (16 * 65) + trow * 65 + cql;
  float* gdst = mean_out + (size_t)(b * TSEG + tbase + trow) * TSEG + cql;

  for (int c = 0; c < 4; ++c) {
#pragma unroll
    for (int j = 0; j < 2; ++j)
#pragma unroll
      for (int jj = 0; jj < 2; ++jj) {
        int st = 4 * c + 2 * j + jj;
        int sl = 32 * j + 4 * jj + 8 * lg;
#pragma unroll
        for (int r = 0; r < 4; ++r) smw[sl + r] = macc[st][r] * 0.125f;
      }
#pragma unroll
    for (int j = 0; j < 4; ++j)
      *reinterpret_cast<f32x4*>(gdst + c * 64 + j * 16) =
          *reinterpret_cast<const f32x4*>(srcp + j * 16);
  }
}

// ---------------- K3: output projection ----------------
__global__ __launch_bounds__(256, 2)
void k_proj(const u16* __restrict__ yb, const u16* __restrict__ wb,
            const float* __restrict__ bp, float* __restrict__ out) {
  const int d = blockIdx.x;
  const int xcd = d & 7, i = d >> 3;          // i in 0..63
  const int m0 = (xcd * 32 + (i >> 1)) * 128;
  const int n0 = (i & 1) * 128;
  const int tid = threadIdx.x;
  const int w = tid >> 6, l = tid & 63;
  const int lr = l & 15, lg = l >> 4;
  const int wr = w >> 1, wc = w & 1;
  const u16* W = wb + 3 * (CEMB * CEMB);

  __shared__ u16 lds[32768];  // 64 KB

  GEMM_MAIN_LOOP(yb, W)

  float bb[4];
#pragma unroll
  for (int nf = 0; nf < 4; ++nf) bb[nf] = bp[n0 + wc * 64 + nf * 16 + lr];
#pragma unroll
  for (int mf = 0; mf < 4; ++mf)
#pragma unroll
    for (int nf = 0; nf < 4; ++nf)
#pragma unroll
      for (int r = 0; r < 4; ++r) {
        int m = m0 + wr * 64 + mf * 16 + lg * 4 + r;
        int c = n0 + wc * 64 + nf * 16 + lr;
        out[(size_t)m * CEMB + c] = acc[mf][nf][r] + bb[nf];
      }
}

extern "C" void kernel_launch(void* const* d_in, const int* in_sizes, int n_in,
                              void* d_out, int out_size, void* d_ws, size_t ws_size,
                              hipStream_t stream) {
  (void)in_sizes; (void)n_in; (void)out_size; (void)ws_size;
  const float* x  = (const float*)d_in[0];
  // d_in[1] = batch indices (unused: equal-length segments, B=128, T=256)
  const float* Wq = (const float*)d_in[2];
  const float* bq = (const float*)d_in[3];
  const float* Wk = (const float*)d_in[4];
  const float* bk = (const float*)d_in[5];
  const float* Wv = (const float*)d_in[6];
  const float* bv = (const float*)d_in[7];
  const float* Wp = (const float*)d_in[8];
  const float* bp = (const float*)d_in[9];
  float* out = (float*)d_out;

  char* ws = (char*)d_ws;
  u16* xb   = (u16*)(ws);                    // 16 MiB (reused as y_ws after k_qkv)
  u16* wb   = (u16*)(ws + 16777216);         // 512 KiB
  u16* q_ws = (u16*)(ws + 17301504);         // 16 MiB, plain [m][256], pre-scaled
  u16* k_ws = (u16*)(ws + 34078720);         // 16 MiB, plain [m][256]
  u16* v_ws = (u16*)(ws + 50855936);         // 16 MiB, transposed [b,h,d,t]
  u16* y_ws = xb;
  float* mean_out = out + (size_t)NTOK * CEMB;

  k_convert<<<4224, 256, 0, stream>>>(x, Wq, Wk, Wv, Wp, xb, wb);
  k_qkv<<<1536, 256, 0, stream>>>(xb, wb, bq, bk, bv, q_ws, k_ws, v_ws);
  k_attn<<<256, 512, 131072, stream>>>(q_ws, k_ws, v_ws, y_ws, mean_out);
  k_proj<<<512, 256, 0, stream>>>(y_ws, wb, bp, out);
}

// Round 12
// 88.678 us; speedup vs baseline: 1.7642x; 1.1192x over previous
//
#include <hip/hip_runtime.h>
#include <hip/hip_bf16.h>
#include <stdint.h>

typedef unsigned short u16;
typedef __bf16 bf16_t;
typedef bf16_t bf16x8 __attribute__((ext_vector_type(8)));
typedef float f32x4 __attribute__((ext_vector_type(4)));

#define NTOK 32768
#define CEMB 256
#define NHEAD 8
#define HD 32
#define BSEG 128
#define TSEG 256

// 1/sqrt(32) * log2(e): folded into Q at projection time.
#define SCQ (0.17677669529663687f * 1.4426950408889634f)

static __device__ __forceinline__ bf16x8 ld16(const u16* p) {
  uint4 v = *reinterpret_cast<const uint4*>(p);
  return __builtin_bit_cast(bf16x8, v);
}
static __device__ __forceinline__ u16 f2b(float f) {
  return __builtin_bit_cast(u16, (bf16_t)f);
}

typedef __attribute__((address_space(1))) const void GASV;
typedef __attribute__((address_space(3))) void LASV;
static __device__ __forceinline__ void stage16(const u16* g, u16* l) {
  __builtin_amdgcn_global_load_lds((GASV*)g, (LASV*)l, 16, 0, 0);
}

// ---------------- K0: convert x and weights to bf16 ----------------
__global__ void k_convert(const float* __restrict__ x,
                          const float* __restrict__ wq, const float* __restrict__ wk,
                          const float* __restrict__ wv, const float* __restrict__ wp,
                          u16* __restrict__ xb, u16* __restrict__ wb) {
  const int XSLOTS = (NTOK * CEMB) / 8;      // 1048576
  const int WSLOTS = (4 * CEMB * CEMB) / 8;  // 32768
  int slot = blockIdx.x * blockDim.x + threadIdx.x;
  if (slot >= XSLOTS + WSLOTS) return;
  const float* src;
  u16* dst;
  if (slot < XSLOTS) {
    src = x + slot * 8;
    dst = xb + slot * 8;
  } else {
    int e = (slot - XSLOTS) * 8;
    int wsel = e >> 16, off = e & 65535;
    const float* s0 = (wsel == 0) ? wq : ((wsel == 1) ? wk : ((wsel == 2) ? wv : wp));
    src = s0 + off;
    dst = wb + e;
  }
  float4 a = reinterpret_cast<const float4*>(src)[0];
  float4 b = reinterpret_cast<const float4*>(src)[1];
  u16 o[8] = {f2b(a.x), f2b(a.y), f2b(a.z), f2b(a.w),
              f2b(b.x), f2b(b.y), f2b(b.z), f2b(b.w)};
  *reinterpret_cast<uint4*>(dst) = *reinterpret_cast<const uint4*>(o);
}

// ======== shared GEMM core pieces (BM=128, BN=128, BK=64, 4 waves 2x2) ========
#define GEMM_MAIN_LOOP(Asrc, Bsrc)                                              \
  f32x4 acc[4][4];                                                              \
  _Pragma("unroll") for (int mf = 0; mf < 4; ++mf)                              \
      _Pragma("unroll") for (int nf = 0; nf < 4; ++nf) {                        \
    f32x4 z = {0.f, 0.f, 0.f, 0.f};                                             \
    acc[mf][nf] = z;                                                            \
  }                                                                             \
  u16* As = lds;                                                                \
  u16* Bs = lds + 16384;                                                        \
  auto STAGE = [&](int buf, int kt) {                                           \
    _Pragma("unroll") for (int i = 0; i < 4; ++i) {                             \
      int cidx = i * 256 + tid;                                                 \
      int row = cidx >> 3;                                                      \
      int scb = ((cidx & 7) << 4) ^ ((row & 7) << 4); /* src col bytes */       \
      u16* dst_lds = As + buf * 8192 + (i * 256 + w * 64) * 8;                  \
      stage16(Asrc + (size_t)(m0 + row) * CEMB + kt * 64 + (scb >> 1), dst_lds);\
      u16* dst_ldsb = Bs + buf * 8192 + (i * 256 + w * 64) * 8;                 \
      stage16(Bsrc + (size_t)(n0 + row) * CEMB + kt * 64 + (scb >> 1), dst_ldsb);\
    }                                                                           \
  };                                                                            \
  STAGE(0, 0);                                                                  \
  __syncthreads();                                                              \
  for (int kt = 0; kt < 4; ++kt) {                                              \
    int buf = kt & 1;                                                           \
    if (kt < 3) STAGE(buf ^ 1, kt + 1);                                         \
    bf16x8 av[4][2], bw[4][2];                                                  \
    _Pragma("unroll") for (int mf = 0; mf < 4; ++mf)                            \
        _Pragma("unroll") for (int kk = 0; kk < 2; ++kk) {                      \
      int row = wr * 64 + mf * 16 + lr;                                         \
      int byte = row * 128 + ((kk * 64 + lg * 16) ^ ((row & 7) << 4));          \
      av[mf][kk] = *reinterpret_cast<const bf16x8*>(                            \
          (const char*)(As + buf * 8192) + byte);                               \
    }                                                                           \
    _Pragma("unroll") for (int nf = 0; nf < 4; ++nf)                            \
        _Pragma("unroll") for (int kk = 0; kk < 2; ++kk) {                      \
      int row = wc * 64 + nf * 16 + lr;                                         \
      int byte = row * 128 + ((kk * 64 + lg * 16) ^ ((row & 7) << 4));          \
      bw[nf][kk] = *reinterpret_cast<const bf16x8*>(                            \
          (const char*)(Bs + buf * 8192) + byte);                               \
    }                                                                           \
    _Pragma("unroll") for (int kk = 0; kk < 2; ++kk)                            \
        _Pragma("unroll") for (int nf = 0; nf < 4; ++nf)                        \
            _Pragma("unroll") for (int mf = 0; mf < 4; ++mf)                    \
      acc[mf][nf] = __builtin_amdgcn_mfma_f32_16x16x32_bf16(                    \
          av[mf][kk], bw[nf][kk], acc[mf][nf], 0, 0, 0);                        \
    __syncthreads();                                                            \
  }

// ---------------- K1: QKV projection GEMMs ----------------
// Q output is pre-scaled by SCQ so k_attn's QK^T feeds exp2 directly.
__global__ __launch_bounds__(256, 2)
void k_qkv(const u16* __restrict__ xb, const u16* __restrict__ wb,
           const float* __restrict__ bq, const float* __restrict__ bk,
           const float* __restrict__ bv,
           u16* __restrict__ q_ws, u16* __restrict__ k_ws, u16* __restrict__ v_ws) {
  const int d = blockIdx.x;
  const int xcd = d & 7, i = d >> 3;          // i in 0..191
  const int m_idx = xcd * 32 + i / 6;         // 0..255
  const int rr = i % 6;
  const int mode = rr >> 1;                   // 0=Q,1=K,2=V
  const int n0 = (rr & 1) * 128;
  const int m0 = m_idx * 128;
  const int tid = threadIdx.x;
  const int w = tid >> 6, l = tid & 63;
  const int lr = l & 15, lg = l >> 4;
  const int wr = w >> 1, wc = w & 1;

  __shared__ u16 lds[32768];  // 64 KB

  const u16* W = wb + mode * (CEMB * CEMB);
  const float* bias = (mode == 0) ? bq : ((mode == 1) ? bk : bv);

  GEMM_MAIN_LOOP(xb, W)

  float bb[4];
#pragma unroll
  for (int nf = 0; nf < 4; ++nf) bb[nf] = bias[n0 + wc * 64 + nf * 16 + lr];

  const float osc = (mode == 0) ? SCQ : 1.0f;

  if (mode < 2) {
    // bounce via LDS -> plain [m][256] bf16 layout, coalesced 16B stores
    u16* Et = lds;
#pragma unroll
    for (int mf = 0; mf < 4; ++mf)
#pragma unroll
      for (int nf = 0; nf < 4; ++nf)
#pragma unroll
        for (int r = 0; r < 4; ++r) {
          int row = wr * 64 + mf * 16 + lg * 4 + r;
          int col = wc * 64 + nf * 16 + lr;
          int byte = (row * 256 + col * 2) ^ ((row & 7) << 4);
          *(u16*)((char*)Et + byte) = f2b((acc[mf][nf][r] + bb[nf]) * osc);
        }
    __syncthreads();
    u16* out = (mode == 0) ? q_ws : k_ws;
    int row_l = tid >> 1, half = tid & 1;
    u16* dstp = out + (size_t)(m0 + row_l) * CEMB + n0 + half * 64;
#pragma unroll
    for (int j = 0; j < 8; ++j) {
      int byte = row_l * 256 + (((half * 64 + j * 8) * 2) ^ ((row_l & 7) << 4));
      *reinterpret_cast<uint4*>(dstp + j * 8) =
          *reinterpret_cast<const uint4*>((const char*)Et + byte);
    }
  } else {
    // V: bounce transposed -> v_ws[b,h,d,t], coalesced 16B stores
    u16* Vt = lds;
#pragma unroll
    for (int mf = 0; mf < 4; ++mf)
#pragma unroll
      for (int nf = 0; nf < 4; ++nf)
#pragma unroll
        for (int r = 0; r < 4; ++r) {
          int row = wr * 64 + mf * 16 + lg * 4 + r;
          int col = wc * 64 + nf * 16 + lr;
          int byte = (col * 256 + row * 2) ^ ((col & 7) << 4);
          *(u16*)((char*)Vt + byte) = f2b(acc[mf][nf][r] + bb[nf]);
        }
    __syncthreads();
    int col_l = tid >> 1, half = tid & 1;
    int c = n0 + col_l, hh = c >> 5, dd = c & 31;
    int bs = m0 >> 8, t0 = m0 & 255;
    u16* dst = v_ws + ((size_t)(bs * NHEAD + hh) * HD + dd) * TSEG + t0 + half * 64;
#pragma unroll
    for (int j = 0; j < 8; ++j) {
      int byte = col_l * 256 + ((half * 128 + j * 16) ^ ((col_l & 7) << 4));
      *reinterpret_cast<uint4*>(dst + j * 8) =
          *reinterpret_cast<const uint4*>((const char*)Vt + byte);
    }
  }
}

// ---------------- K2: attention ----------------
// Block = (b, t-half), 1024 threads = 16 waves = 8 t-tiles x 2 s-halves.
// Wave (wt, sh): 16 t-rows vs s in [sh*128, sh*128+128), all heads serial.
// Staging identical to R9 (one block-wide stream, each head once) -> same
// fetch. Deferred normalization makes the s-split combine cheap: partial
// raw-P PV y_raw + partial sum sm per wave; ONE lgkm-only barrier exchanges
// sm + one dt-half of y_raw via LDS (stage gloads stay in flight across it);
// inv = rcp(sm0+sm1); each wave stores its dt=sh output half. No-max
// softmax (validated R11). Mean rows are s-disjoint -> no mean combine.
// LDS: K dbuf 32KB | V dbuf 32KB | smbuf 1KB | ybuf 17KB = 84KB -> 1 blk/CU,
// 16 waves/CU.
__global__ __launch_bounds__(1024, 4)
void k_attn(const u16* __restrict__ q_ws, const u16* __restrict__ k_ws,
            const u16* __restrict__ v_ws,
            u16* __restrict__ y_ws, float* __restrict__ mean_out) {
  const int dblk = blockIdx.x;
  const int xcd = dblk & 7, ii = dblk >> 3;  // ii in 0..31
  const int b = xcd * 16 + (ii >> 1);
  const int th = ii & 1;
  const int tid = threadIdx.x;
  const int w = tid >> 6, l = tid & 63;
  const int lr = l & 15, lg = l >> 4;
  const int wt = w & 7, sh = w >> 3;
  const int tbase = th * 128 + wt * 16;

  extern __shared__ u16 ldsKV[];
  // u16 offsets: K dbuf [2][1024ch][8] at 0 (32KB) ; V dbuf at 16384 (32KB)
  // f32 regions: smbuf at byte 65536 (16 slots x 16 f32); ybuf at byte 66560
  //              (16 slots x 272 f32: addr = slot*272 + lg*68 + lr*4 + r)
  float* smb = reinterpret_cast<float*>(ldsKV + 32768);
  float* ylds = reinterpret_cast<float*>(ldsKV + 33280);

  float macc[8][4];
#pragma unroll
  for (int st = 0; st < 8; ++st)
#pragma unroll
    for (int r = 0; r < 4; ++r) macc[st][r] = 0.f;

  const u16* qseg = q_ws + (size_t)b * TSEG * CEMB;
  const u16* kseg = k_ws + (size_t)b * TSEG * CEMB;
  const u16* vseg = v_ws + (size_t)(b * NHEAD) * HD * TSEG;

  // stage K+V for head hn into dbuf slot bn (1024 threads, 2 stage16 each)
  auto STAGE_KV = [&](int hn, int bn) {
    int idx = tid;                       // 0..1023 chunk id
    int c = idx >> 6, l2 = idx & 63;     // frag, lane
    int lr2 = l2 & 15, lg2 = l2 >> 4;
    int srow = 32 * (c >> 1) + 4 * (c & 1) + 8 * (lr2 >> 2) + (lr2 & 3);
    stage16(kseg + srow * CEMB + hn * HD + lg2 * 8, ldsKV + (bn * 1024 + idx) * 8);
    int vrow = (c >> 3) * 16 + lr2;
    int vcol = (c & 7) * 32 + lg2 * 8;
    stage16(vseg + (size_t)(hn * HD + vrow) * TSEG + vcol,
            ldsKV + 16384 + (bn * 1024 + idx) * 8);
  };

  STAGE_KV(0, 0);
  bf16x8 qf = ld16(qseg + (tbase + lr) * CEMB + lg * 8);

  const int own_slot = wt * 2 + sh;
  const int par_slot = wt * 2 + (1 - sh);

  for (int h = 0; h < NHEAD; ++h) {
    const int bn = h & 1;
    __syncthreads();  // B1: vmcnt drain (stage h + qf) + barrier
    if (h < 7) STAGE_KV(h + 1, bn ^ 1);
    const u16* Kb = ldsKV + bn * 8192;
    const u16* Vb = ldsKV + 16384 + bn * 8192;

    // QK for this wave's s-half: frags sfrag = sh*8 + st
    float s[8][4];
#pragma unroll
    for (int st = 0; st < 8; ++st) {
      bf16x8 kf = *reinterpret_cast<const bf16x8*>(Kb + ((sh * 8 + st) * 64 + l) * 8);
      f32x4 z = {0.f, 0.f, 0.f, 0.f};
      f32x4 dd = __builtin_amdgcn_mfma_f32_16x16x32_bf16(kf, qf, z, 0, 0, 0);
#pragma unroll
      for (int r = 0; r < 4; ++r) s[st][r] = dd[r];
    }

    // prefetch Q for next head
    qf = ld16(qseg + (tbase + lr) * CEMB + ((h + 1) & 7) * HD + lg * 8);

    // no-max exp2 + 4-way parallel partial sums (this s-half)
    float s0 = 0.f, s1 = 0.f, s2 = 0.f, s3 = 0.f;
#pragma unroll
    for (int st = 0; st < 8; ++st) {
      float p0 = exp2f(s[st][0]);
      float p1 = exp2f(s[st][1]);
      float p2 = exp2f(s[st][2]);
      float p3 = exp2f(s[st][3]);
      s[st][0] = p0; s[st][1] = p1; s[st][2] = p2; s[st][3] = p3;
      s0 += p0; s1 += p1; s2 += p2; s3 += p3;
    }
    float sm = (s0 + s1) + (s2 + s3);
    sm += __shfl_xor(sm, 16, 64);
    sm += __shfl_xor(sm, 32, 64);

    // pack raw P fragments for this s-half (4 global kk = sh*4 + kk')
    bf16x8 pb[4];
#pragma unroll
    for (int kk = 0; kk < 4; ++kk)
#pragma unroll
      for (int e = 0; e < 4; ++e) {
        pb[kk][e] = (bf16_t)s[2 * kk][e];
        pb[kk][4 + e] = (bf16_t)s[2 * kk + 1][e];
      }

    // partial PV (raw), both dt halves
    f32x4 y0 = {0.f, 0.f, 0.f, 0.f}, y1 = {0.f, 0.f, 0.f, 0.f};
#pragma unroll
    for (int kk = 0; kk < 4; ++kk) {
      bf16x8 vf0 = *reinterpret_cast<const bf16x8*>(Vb + ((0 * 8 + sh * 4 + kk) * 64 + l) * 8);
      bf16x8 vf1 = *reinterpret_cast<const bf16x8*>(Vb + ((1 * 8 + sh * 4 + kk) * 64 + l) * 8);
      y0 = __builtin_amdgcn_mfma_f32_16x16x32_bf16(vf0, pb[kk], y0, 0, 0, 0);
      y1 = __builtin_amdgcn_mfma_f32_16x16x32_bf16(vf1, pb[kk], y1, 0, 0, 0);
    }

    // publish partials: sm scalar + the dt-half the partner combines (dt=1-sh)
    if (l < 16) smb[own_slot * 16 + l] = sm;
    {
      f32x4 ywr = (sh == 0) ? y1 : y0;  // wave combines dt==sh, publishes other
      *reinterpret_cast<f32x4*>(ylds + own_slot * 272 + lg * 68 + lr * 4) = ywr;
    }

    // B2: lgkm-only barrier — stage(h+1) gloads stay in flight (no vmcnt drain)
    __builtin_amdgcn_sched_barrier(0);
    asm volatile("s_waitcnt lgkmcnt(0)" ::: "memory");
    __builtin_amdgcn_s_barrier();
    __builtin_amdgcn_sched_barrier(0);

    float smT = sm + smb[par_slot * 16 + lr];
    float inv = __builtin_amdgcn_rcpf(smT);

    // mean accumulate (this wave's s-rows only; normalized)
#pragma unroll
    for (int st = 0; st < 8; ++st)
#pragma unroll
      for (int r = 0; r < 4; ++r)
        macc[st][r] = fmaf(s[st][r], inv, macc[st][r]);

    // combine dt=sh half: own partial + partner's published partial
    {
      f32x4 ymine = (sh == 0) ? y0 : y1;
      f32x4 ypar = *reinterpret_cast<const f32x4*>(ylds + par_slot * 272 + lg * 68 + lr * 4);
      u16 o[4];
#pragma unroll
      for (int r = 0; r < 4; ++r) o[r] = f2b((ymine[r] + ypar[r]) * inv);
      *reinterpret_cast<uint2*>(
          y_ws + (size_t)(b * TSEG + tbase + lr) * CEMB + h * HD + sh * 16 + lg * 4) =
          *reinterpret_cast<const uint2*>(o);
    }
  }

  __syncthreads();  // protect LDS before reuse as mean staging

  // head-mean epilogue: wave-private staging, 2 s-chunks of 64 (this s-half).
  float* smem = reinterpret_cast<float*>(ldsKV);
  float* smw = smem + w * (16 * 65) + lr * 65;
  const int trow = l >> 2;
  const int cql = (l & 3) * 4;
  const float* srcp = smem + w * (16 * 65) + trow * 65 + cql;
  float* gdst = mean_out + (size_t)(b * TSEG + tbase + trow) * TSEG + sh * 128 + cql;

  for (int c = 0; c < 2; ++c) {
#pragma unroll
    for (int j = 0; j < 4; ++j) {
      int st = 4 * c + j;
      int sl = 32 * ((st >> 1) & 1) + 4 * (st & 1) + 8 * lg;
#pragma unroll
      for (int r = 0; r < 4; ++r) smw[sl + r] = macc[st][r] * 0.125f;
    }
#pragma unroll
    for (int j = 0; j < 4; ++j)
      *reinterpret_cast<f32x4*>(gdst + c * 64 + j * 16) =
          *reinterpret_cast<const f32x4*>(srcp + j * 16);
  }
}

// ---------------- K3: output projection ----------------
__global__ __launch_bounds__(256, 2)
void k_proj(const u16* __restrict__ yb, const u16* __restrict__ wb,
            const float* __restrict__ bp, float* __restrict__ out) {
  const int d = blockIdx.x;
  const int xcd = d & 7, i = d >> 3;          // i in 0..63
  const int m0 = (xcd * 32 + (i >> 1)) * 128;
  const int n0 = (i & 1) * 128;
  const int tid = threadIdx.x;
  const int w = tid >> 6, l = tid & 63;
  const int lr = l & 15, lg = l >> 4;
  const int wr = w >> 1, wc = w & 1;
  const u16* W = wb + 3 * (CEMB * CEMB);

  __shared__ u16 lds[32768];  // 64 KB

  GEMM_MAIN_LOOP(yb, W)

  float bb[4];
#pragma unroll
  for (int nf = 0; nf < 4; ++nf) bb[nf] = bp[n0 + wc * 64 + nf * 16 + lr];
#pragma unroll
  for (int mf = 0; mf < 4; ++mf)
#pragma unroll
    for (int nf = 0; nf < 4; ++nf)
#pragma unroll
      for (int r = 0; r < 4; ++r) {
        int m = m0 + wr * 64 + mf * 16 + lg * 4 + r;
        int c = n0 + wc * 64 + nf * 16 + lr;
        out[(size_t)m * CEMB + c] = acc[mf][nf][r] + bb[nf];
      }
}

extern "C" void kernel_launch(void* const* d_in, const int* in_sizes, int n_in,
                              void* d_out, int out_size, void* d_ws, size_t ws_size,
                              hipStream_t stream) {
  (void)in_sizes; (void)n_in; (void)out_size; (void)ws_size;
  const float* x  = (const float*)d_in[0];
  // d_in[1] = batch indices (unused: equal-length segments, B=128, T=256)
  const float* Wq = (const float*)d_in[2];
  const float* bq = (const float*)d_in[3];
  const float* Wk = (const float*)d_in[4];
  const float* bk = (const float*)d_in[5];
  const float* Wv = (const float*)d_in[6];
  const float* bv = (const float*)d_in[7];
  const float* Wp = (const float*)d_in[8];
  const float* bp = (const float*)d_in[9];
  float* out = (float*)d_out;

  char* ws = (char*)d_ws;
  u16* xb   = (u16*)(ws);                    // 16 MiB (reused as y_ws after k_qkv)
  u16* wb   = (u16*)(ws + 16777216);         // 512 KiB
  u16* q_ws = (u16*)(ws + 17301504);         // 16 MiB, plain [m][256], pre-scaled
  u16* k_ws = (u16*)(ws + 34078720);         // 16 MiB, plain [m][256]
  u16* v_ws = (u16*)(ws + 50855936);         // 16 MiB, transposed [b,h,d,t]
  u16* y_ws = xb;
  float* mean_out = out + (size_t)NTOK * CEMB;

  k_convert<<<4224, 256, 0, stream>>>(x, Wq, Wk, Wv, Wp, xb, wb);
  k_qkv<<<1536, 256, 0, stream>>>(xb, wb, bq, bk, bv, q_ws, k_ws, v_ws);
  k_attn<<<256, 1024, 83968, stream>>>(q_ws, k_ws, v_ws, y_ws, mean_out);
  k_proj<<<512, 256, 0, stream>>>(y_ws, wb, bp, out);
}

// Round 13
// 84.604 us; speedup vs baseline: 1.8491x; 1.0481x over previous
//
#include <hip/hip_runtime.h>
#include <hip/hip_bf16.h>
#include <stdint.h>

typedef unsigned short u16;
typedef __bf16 bf16_t;
typedef bf16_t bf16x8 __attribute__((ext_vector_type(8)));
typedef float f32x4 __attribute__((ext_vector_type(4)));

#define NTOK 32768
#define CEMB 256
#define NHEAD 8
#define HD 32
#define BSEG 128
#define TSEG 256

// 1/sqrt(32) * log2(e): folded into Q at projection time.
#define SCQ (0.17677669529663687f * 1.4426950408889634f)

static __device__ __forceinline__ bf16x8 ld16(const u16* p) {
  uint4 v = *reinterpret_cast<const uint4*>(p);
  return __builtin_bit_cast(bf16x8, v);
}
static __device__ __forceinline__ u16 f2b(float f) {
  return __builtin_bit_cast(u16, (bf16_t)f);
}

typedef __attribute__((address_space(1))) const void GASV;
typedef __attribute__((address_space(3))) void LASV;
static __device__ __forceinline__ void stage16(const u16* g, u16* l) {
  __builtin_amdgcn_global_load_lds((GASV*)g, (LASV*)l, 16, 0, 0);
}

// ---------------- K0: convert x and weights to bf16 ----------------
__global__ void k_convert(const float* __restrict__ x,
                          const float* __restrict__ wq, const float* __restrict__ wk,
                          const float* __restrict__ wv, const float* __restrict__ wp,
                          u16* __restrict__ xb, u16* __restrict__ wb) {
  const int XSLOTS = (NTOK * CEMB) / 8;      // 1048576
  const int WSLOTS = (4 * CEMB * CEMB) / 8;  // 32768
  int slot = blockIdx.x * blockDim.x + threadIdx.x;
  if (slot >= XSLOTS + WSLOTS) return;
  const float* src;
  u16* dst;
  if (slot < XSLOTS) {
    src = x + slot * 8;
    dst = xb + slot * 8;
  } else {
    int e = (slot - XSLOTS) * 8;
    int wsel = e >> 16, off = e & 65535;
    const float* s0 = (wsel == 0) ? wq : ((wsel == 1) ? wk : ((wsel == 2) ? wv : wp));
    src = s0 + off;
    dst = wb + e;
  }
  float4 a = reinterpret_cast<const float4*>(src)[0];
  float4 b = reinterpret_cast<const float4*>(src)[1];
  u16 o[8] = {f2b(a.x), f2b(a.y), f2b(a.z), f2b(a.w),
              f2b(b.x), f2b(b.y), f2b(b.z), f2b(b.w)};
  *reinterpret_cast<uint4*>(dst) = *reinterpret_cast<const uint4*>(o);
}

// ======== shared GEMM core pieces (BM=128, BN=128, BK=64, 4 waves 2x2) ========
#define GEMM_MAIN_LOOP(Asrc, Bsrc)                                              \
  f32x4 acc[4][4];                                                              \
  _Pragma("unroll") for (int mf = 0; mf < 4; ++mf)                              \
      _Pragma("unroll") for (int nf = 0; nf < 4; ++nf) {                        \
    f32x4 z = {0.f, 0.f, 0.f, 0.f};                                             \
    acc[mf][nf] = z;                                                            \
  }                                                                             \
  u16* As = lds;                                                                \
  u16* Bs = lds + 16384;                                                        \
  auto STAGE = [&](int buf, int kt) {                                           \
    _Pragma("unroll") for (int i = 0; i < 4; ++i) {                             \
      int cidx = i * 256 + tid;                                                 \
      int row = cidx >> 3;                                                      \
      int scb = ((cidx & 7) << 4) ^ ((row & 7) << 4); /* src col bytes */       \
      u16* dst_lds = As + buf * 8192 + (i * 256 + w * 64) * 8;                  \
      stage16(Asrc + (size_t)(m0 + row) * CEMB + kt * 64 + (scb >> 1), dst_lds);\
      u16* dst_ldsb = Bs + buf * 8192 + (i * 256 + w * 64) * 8;                 \
      stage16(Bsrc + (size_t)(n0 + row) * CEMB + kt * 64 + (scb >> 1), dst_ldsb);\
    }                                                                           \
  };                                                                            \
  STAGE(0, 0);                                                                  \
  __syncthreads();                                                              \
  for (int kt = 0; kt < 4; ++kt) {                                              \
    int buf = kt & 1;                                                           \
    if (kt < 3) STAGE(buf ^ 1, kt + 1);                                         \
    bf16x8 av[4][2], bw[4][2];                                                  \
    _Pragma("unroll") for (int mf = 0; mf < 4; ++mf)                            \
        _Pragma("unroll") for (int kk = 0; kk < 2; ++kk) {                      \
      int row = wr * 64 + mf * 16 + lr;                                         \
      int byte = row * 128 + ((kk * 64 + lg * 16) ^ ((row & 7) << 4));          \
      av[mf][kk] = *reinterpret_cast<const bf16x8*>(                            \
          (const char*)(As + buf * 8192) + byte);                               \
    }                                                                           \
    _Pragma("unroll") for (int nf = 0; nf < 4; ++nf)                            \
        _Pragma("unroll") for (int kk = 0; kk < 2; ++kk) {                      \
      int row = wc * 64 + nf * 16 + lr;                                         \
      int byte = row * 128 + ((kk * 64 + lg * 16) ^ ((row & 7) << 4));          \
      bw[nf][kk] = *reinterpret_cast<const bf16x8*>(                            \
          (const char*)(Bs + buf * 8192) + byte);                               \
    }                                                                           \
    _Pragma("unroll") for (int kk = 0; kk < 2; ++kk)                            \
        _Pragma("unroll") for (int nf = 0; nf < 4; ++nf)                        \
            _Pragma("unroll") for (int mf = 0; mf < 4; ++mf)                    \
      acc[mf][nf] = __builtin_amdgcn_mfma_f32_16x16x32_bf16(                    \
          av[mf][kk], bw[nf][kk], acc[mf][nf], 0, 0, 0);                        \
    __syncthreads();                                                            \
  }

// ---------------- K1: QKV projection GEMMs ----------------
// Q output is pre-scaled by SCQ so k_attn's QK^T feeds exp2 directly.
__global__ __launch_bounds__(256, 2)
void k_qkv(const u16* __restrict__ xb, const u16* __restrict__ wb,
           const float* __restrict__ bq, const float* __restrict__ bk,
           const float* __restrict__ bv,
           u16* __restrict__ q_ws, u16* __restrict__ k_ws, u16* __restrict__ v_ws) {
  const int d = blockIdx.x;
  const int xcd = d & 7, i = d >> 3;          // i in 0..191
  const int m_idx = xcd * 32 + i / 6;         // 0..255
  const int rr = i % 6;
  const int mode = rr >> 1;                   // 0=Q,1=K,2=V
  const int n0 = (rr & 1) * 128;
  const int m0 = m_idx * 128;
  const int tid = threadIdx.x;
  const int w = tid >> 6, l = tid & 63;
  const int lr = l & 15, lg = l >> 4;
  const int wr = w >> 1, wc = w & 1;

  __shared__ u16 lds[32768];  // 64 KB

  const u16* W = wb + mode * (CEMB * CEMB);
  const float* bias = (mode == 0) ? bq : ((mode == 1) ? bk : bv);

  GEMM_MAIN_LOOP(xb, W)

  float bb[4];
#pragma unroll
  for (int nf = 0; nf < 4; ++nf) bb[nf] = bias[n0 + wc * 64 + nf * 16 + lr];

  const float osc = (mode == 0) ? SCQ : 1.0f;

  if (mode < 2) {
    // bounce via LDS -> plain [m][256] bf16 layout, coalesced 16B stores
    u16* Et = lds;
#pragma unroll
    for (int mf = 0; mf < 4; ++mf)
#pragma unroll
      for (int nf = 0; nf < 4; ++nf)
#pragma unroll
        for (int r = 0; r < 4; ++r) {
          int row = wr * 64 + mf * 16 + lg * 4 + r;
          int col = wc * 64 + nf * 16 + lr;
          int byte = (row * 256 + col * 2) ^ ((row & 7) << 4);
          *(u16*)((char*)Et + byte) = f2b((acc[mf][nf][r] + bb[nf]) * osc);
        }
    __syncthreads();
    u16* out = (mode == 0) ? q_ws : k_ws;
    int row_l = tid >> 1, half = tid & 1;
    u16* dstp = out + (size_t)(m0 + row_l) * CEMB + n0 + half * 64;
#pragma unroll
    for (int j = 0; j < 8; ++j) {
      int byte = row_l * 256 + (((half * 64 + j * 8) * 2) ^ ((row_l & 7) << 4));
      *reinterpret_cast<uint4*>(dstp + j * 8) =
          *reinterpret_cast<const uint4*>((const char*)Et + byte);
    }
  } else {
    // V: bounce transposed -> v_ws[b,h,d,t], coalesced 16B stores
    u16* Vt = lds;
#pragma unroll
    for (int mf = 0; mf < 4; ++mf)
#pragma unroll
      for (int nf = 0; nf < 4; ++nf)
#pragma unroll
        for (int r = 0; r < 4; ++r) {
          int row = wr * 64 + mf * 16 + lg * 4 + r;
          int col = wc * 64 + nf * 16 + lr;
          int byte = (col * 256 + row * 2) ^ ((col & 7) << 4);
          *(u16*)((char*)Vt + byte) = f2b(acc[mf][nf][r] + bb[nf]);
        }
    __syncthreads();
    int col_l = tid >> 1, half = tid & 1;
    int c = n0 + col_l, hh = c >> 5, dd = c & 31;
    int bs = m0 >> 8, t0 = m0 & 255;
    u16* dst = v_ws + ((size_t)(bs * NHEAD + hh) * HD + dd) * TSEG + t0 + half * 64;
#pragma unroll
    for (int j = 0; j < 8; ++j) {
      int byte = col_l * 256 + ((half * 128 + j * 16) ^ ((col_l & 7) << 4));
      *reinterpret_cast<uint4*>(dst + j * 8) =
          *reinterpret_cast<const uint4*>((const char*)Vt + byte);
    }
  }
}

// ---------------- K2: attention + fused output projection ----------------
// R12 structure: block = (b, t-half), 1024 threads = 16 waves = 8 t x 2 s.
// y is now written (bf16) to an XOR-swizzled LDS tile instead of global;
// after the head loop: mean epilogue, then in-block GEMM out = y*Wp^T + bp
// with Wp staged double-buffered into the freed KV region.
// LDS map (bytes): [0,65536) KV dbuf | [65536,66560) smb | [66560,83968)
// ybuf | [83968,149504) yTile[128][512B] swizzled. Total 146 KB, 1 blk/CU.
__global__ __launch_bounds__(1024, 4)
void k_attn(const u16* __restrict__ q_ws, const u16* __restrict__ k_ws,
            const u16* __restrict__ v_ws, const u16* __restrict__ wb,
            const float* __restrict__ bp,
            float* __restrict__ out, float* __restrict__ mean_out) {
  const int dblk = blockIdx.x;
  const int xcd = dblk & 7, ii = dblk >> 3;  // ii in 0..31
  const int b = xcd * 16 + (ii >> 1);
  const int th = ii & 1;
  const int tid = threadIdx.x;
  const int w = tid >> 6, l = tid & 63;
  const int lr = l & 15, lg = l >> 4;
  const int wt = w & 7, sh = w >> 3;
  const int tbase = th * 128 + wt * 16;

  extern __shared__ u16 ldsKV[];
  float* smb = reinterpret_cast<float*>(ldsKV + 32768);
  float* ylds = reinterpret_cast<float*>(ldsKV + 33280);
  char* yTile = reinterpret_cast<char*>(ldsKV) + 83968;

  float macc[8][4];
#pragma unroll
  for (int st = 0; st < 8; ++st)
#pragma unroll
    for (int r = 0; r < 4; ++r) macc[st][r] = 0.f;

  const u16* qseg = q_ws + (size_t)b * TSEG * CEMB;
  const u16* kseg = k_ws + (size_t)b * TSEG * CEMB;
  const u16* vseg = v_ws + (size_t)(b * NHEAD) * HD * TSEG;

  auto STAGE_KV = [&](int hn, int bn) {
    int idx = tid;                       // 0..1023 chunk id
    int c = idx >> 6, l2 = idx & 63;     // frag, lane
    int lr2 = l2 & 15, lg2 = l2 >> 4;
    int srow = 32 * (c >> 1) + 4 * (c & 1) + 8 * (lr2 >> 2) + (lr2 & 3);
    stage16(kseg + srow * CEMB + hn * HD + lg2 * 8, ldsKV + (bn * 1024 + idx) * 8);
    int vrow = (c >> 3) * 16 + lr2;
    int vcol = (c & 7) * 32 + lg2 * 8;
    stage16(vseg + (size_t)(hn * HD + vrow) * TSEG + vcol,
            ldsKV + 16384 + (bn * 1024 + idx) * 8);
  };

  STAGE_KV(0, 0);
  bf16x8 qf = ld16(qseg + (tbase + lr) * CEMB + lg * 8);

  const int own_slot = wt * 2 + sh;
  const int par_slot = wt * 2 + (1 - sh);

  for (int h = 0; h < NHEAD; ++h) {
    const int bn = h & 1;
    __syncthreads();  // B1: vmcnt drain (stage h + qf) + barrier
    if (h < 7) STAGE_KV(h + 1, bn ^ 1);
    const u16* Kb = ldsKV + bn * 8192;
    const u16* Vb = ldsKV + 16384 + bn * 8192;

    // QK for this wave's s-half
    float s[8][4];
#pragma unroll
    for (int st = 0; st < 8; ++st) {
      bf16x8 kf = *reinterpret_cast<const bf16x8*>(Kb + ((sh * 8 + st) * 64 + l) * 8);
      f32x4 z = {0.f, 0.f, 0.f, 0.f};
      f32x4 dd = __builtin_amdgcn_mfma_f32_16x16x32_bf16(kf, qf, z, 0, 0, 0);
#pragma unroll
      for (int r = 0; r < 4; ++r) s[st][r] = dd[r];
    }

    qf = ld16(qseg + (tbase + lr) * CEMB + ((h + 1) & 7) * HD + lg * 8);

    // no-max exp2 + 4-way parallel partial sums
    float s0 = 0.f, s1 = 0.f, s2 = 0.f, s3 = 0.f;
#pragma unroll
    for (int st = 0; st < 8; ++st) {
      float p0 = exp2f(s[st][0]);
      float p1 = exp2f(s[st][1]);
      float p2 = exp2f(s[st][2]);
      float p3 = exp2f(s[st][3]);
      s[st][0] = p0; s[st][1] = p1; s[st][2] = p2; s[st][3] = p3;
      s0 += p0; s1 += p1; s2 += p2; s3 += p3;
    }
    float sm = (s0 + s1) + (s2 + s3);
    sm += __shfl_xor(sm, 16, 64);
    sm += __shfl_xor(sm, 32, 64);

    bf16x8 pb[4];
#pragma unroll
    for (int kk = 0; kk < 4; ++kk)
#pragma unroll
      for (int e = 0; e < 4; ++e) {
        pb[kk][e] = (bf16_t)s[2 * kk][e];
        pb[kk][4 + e] = (bf16_t)s[2 * kk + 1][e];
      }

    f32x4 y0 = {0.f, 0.f, 0.f, 0.f}, y1 = {0.f, 0.f, 0.f, 0.f};
#pragma unroll
    for (int kk = 0; kk < 4; ++kk) {
      bf16x8 vf0 = *reinterpret_cast<const bf16x8*>(Vb + ((0 * 8 + sh * 4 + kk) * 64 + l) * 8);
      bf16x8 vf1 = *reinterpret_cast<const bf16x8*>(Vb + ((1 * 8 + sh * 4 + kk) * 64 + l) * 8);
      y0 = __builtin_amdgcn_mfma_f32_16x16x32_bf16(vf0, pb[kk], y0, 0, 0, 0);
      y1 = __builtin_amdgcn_mfma_f32_16x16x32_bf16(vf1, pb[kk], y1, 0, 0, 0);
    }

    if (l < 16) smb[own_slot * 16 + l] = sm;
    {
      f32x4 ywr = (sh == 0) ? y1 : y0;
      *reinterpret_cast<f32x4*>(ylds + own_slot * 272 + lg * 68 + lr * 4) = ywr;
    }

    // B2: lgkm-only barrier — stage(h+1) gloads stay in flight
    __builtin_amdgcn_sched_barrier(0);
    asm volatile("s_waitcnt lgkmcnt(0)" ::: "memory");
    __builtin_amdgcn_s_barrier();
    __builtin_amdgcn_sched_barrier(0);

    float smT = sm + smb[par_slot * 16 + lr];
    float inv = __builtin_amdgcn_rcpf(smT);

#pragma unroll
    for (int st = 0; st < 8; ++st)
#pragma unroll
      for (int r = 0; r < 4; ++r)
        macc[st][r] = fmaf(s[st][r], inv, macc[st][r]);

    // combine dt=sh half -> swizzled LDS y tile (bf16)
    {
      f32x4 ymine = (sh == 0) ? y0 : y1;
      f32x4 ypar = *reinterpret_cast<const f32x4*>(ylds + par_slot * 272 + lg * 68 + lr * 4);
      u16 o[4];
#pragma unroll
      for (int r = 0; r < 4; ++r) o[r] = f2b((ymine[r] + ypar[r]) * inv);
      int row = wt * 16 + lr;
      int colb = h * 64 + sh * 32 + lg * 8;
      *reinterpret_cast<uint2*>(yTile + row * 512 + (colb ^ ((row & 7) << 4))) =
          *reinterpret_cast<const uint2*>(o);
    }
  }

  __syncthreads();  // yTile complete; KV region free

  // ---- head-mean epilogue (wave-private staging in KV region) ----
  {
    float* smem = reinterpret_cast<float*>(ldsKV);
    float* smw = smem + w * (16 * 65) + lr * 65;
    const int trow = l >> 2;
    const int cql = (l & 3) * 4;
    const float* srcp = smem + w * (16 * 65) + trow * 65 + cql;
    float* gdst = mean_out + (size_t)(b * TSEG + tbase + trow) * TSEG + sh * 128 + cql;
    for (int c = 0; c < 2; ++c) {
#pragma unroll
      for (int j = 0; j < 4; ++j) {
        int st = 4 * c + j;
        int sl = 32 * ((st >> 1) & 1) + 4 * (st & 1) + 8 * lg;
#pragma unroll
        for (int r = 0; r < 4; ++r) smw[sl + r] = macc[st][r] * 0.125f;
      }
#pragma unroll
      for (int j = 0; j < 4; ++j)
        *reinterpret_cast<f32x4*>(gdst + c * 64 + j * 16) =
            *reinterpret_cast<const f32x4*>(srcp + j * 16);
    }
  }
  __syncthreads();  // mean staging done; KV region free for W dbuf

  // ---- fused output projection: out = y * Wp^T + bp ----
  // 16 waves = 4 m-tiles(32) x 4 n-tiles(64); W staged dbuf in KV region.
  {
    const u16* wbP = wb + 3 * (CEMB * CEMB);
    const int wrP = w >> 2, wcP = w & 3;

    auto STAGE_W = [&](int kt, int bn) {
      u16* Wb = ldsKV + bn * 16384;
#pragma unroll
      for (int r = 0; r < 2; ++r) {
        int cidx = (r * 16 + w) * 64 + l;
        int row = cidx >> 3;
        int scb = ((cidx & 7) << 4) ^ ((row & 7) << 4);
        stage16(wbP + (size_t)row * CEMB + kt * 64 + (scb >> 1),
                Wb + (r * 16 + w) * 512);
      }
    };

    f32x4 acc[2][4];
#pragma unroll
    for (int mf = 0; mf < 2; ++mf)
#pragma unroll
      for (int nf = 0; nf < 4; ++nf) {
        f32x4 z = {0.f, 0.f, 0.f, 0.f};
        acc[mf][nf] = z;
      }

    STAGE_W(0, 0);
    __syncthreads();
    for (int kt = 0; kt < 4; ++kt) {
      int buf = kt & 1;
      if (kt < 3) STAGE_W(kt + 1, buf ^ 1);
      const char* Wb = (const char*)(ldsKV + buf * 16384);
      bf16x8 av[2][2], bw[4][2];
#pragma unroll
      for (int mf = 0; mf < 2; ++mf)
#pragma unroll
        for (int kk = 0; kk < 2; ++kk) {
          int row = wrP * 32 + mf * 16 + lr;
          int byte = row * 512 + ((kt * 128 + kk * 64 + lg * 16) ^ ((row & 7) << 4));
          av[mf][kk] = *reinterpret_cast<const bf16x8*>(yTile + byte);
        }
#pragma unroll
      for (int nf = 0; nf < 4; ++nf)
#pragma unroll
        for (int kk = 0; kk < 2; ++kk) {
          int row = wcP * 64 + nf * 16 + lr;
          int byte = row * 128 + ((kk * 64 + lg * 16) ^ ((row & 7) << 4));
          bw[nf][kk] = *reinterpret_cast<const bf16x8*>(Wb + byte);
        }
#pragma unroll
      for (int kk = 0; kk < 2; ++kk)
#pragma unroll
        for (int nf = 0; nf < 4; ++nf)
#pragma unroll
          for (int mf = 0; mf < 2; ++mf)
            acc[mf][nf] = __builtin_amdgcn_mfma_f32_16x16x32_bf16(
                av[mf][kk], bw[nf][kk], acc[mf][nf], 0, 0, 0);
      __syncthreads();
    }

    float bb[4];
#pragma unroll
    for (int nf = 0; nf < 4; ++nf) bb[nf] = bp[wcP * 64 + nf * 16 + lr];
#pragma unroll
    for (int mf = 0; mf < 2; ++mf)
#pragma unroll
      for (int nf = 0; nf < 4; ++nf)
#pragma unroll
        for (int r = 0; r < 4; ++r) {
          int m = b * TSEG + th * 128 + wrP * 32 + mf * 16 + lg * 4 + r;
          int c = wcP * 64 + nf * 16 + lr;
          out[(size_t)m * CEMB + c] = acc[mf][nf][r] + bb[nf];
        }
  }
}

extern "C" void kernel_launch(void* const* d_in, const int* in_sizes, int n_in,
                              void* d_out, int out_size, void* d_ws, size_t ws_size,
                              hipStream_t stream) {
  (void)in_sizes; (void)n_in; (void)out_size; (void)ws_size;
  const float* x  = (const float*)d_in[0];
  // d_in[1] = batch indices (unused: equal-length segments, B=128, T=256)
  const float* Wq = (const float*)d_in[2];
  const float* bq = (const float*)d_in[3];
  const float* Wk = (const float*)d_in[4];
  const float* bk = (const float*)d_in[5];
  const float* Wv = (const float*)d_in[6];
  const float* bv = (const float*)d_in[7];
  const float* Wp = (const float*)d_in[8];
  const float* bp = (const float*)d_in[9];
  float* out = (float*)d_out;

  char* ws = (char*)d_ws;
  u16* xb   = (u16*)(ws);                    // 16 MiB
  u16* wb   = (u16*)(ws + 16777216);         // 512 KiB
  u16* q_ws = (u16*)(ws + 17301504);         // 16 MiB, plain [m][256], pre-scaled
  u16* k_ws = (u16*)(ws + 34078720);         // 16 MiB, plain [m][256]
  u16* v_ws = (u16*)(ws + 50855936);         // 16 MiB, transposed [b,h,d,t]
  float* mean_out = out + (size_t)NTOK * CEMB;

  k_convert<<<4224, 256, 0, stream>>>(x, Wq, Wk, Wv, Wp, xb, wb);
  k_qkv<<<1536, 256, 0, stream>>>(xb, wb, bq, bk, bv, q_ws, k_ws, v_ws);
  k_attn<<<256, 1024, 149504, stream>>>(q_ws, k_ws, v_ws, wb, bp, out, mean_out);
}

// Round 14
// 83.475 us; speedup vs baseline: 1.8742x; 1.0135x over previous
//
#include <hip/hip_runtime.h>
#include <hip/hip_bf16.h>
#include <stdint.h>

typedef unsigned short u16;
typedef __bf16 bf16_t;
typedef bf16_t bf16x8 __attribute__((ext_vector_type(8)));
typedef float f32x4 __attribute__((ext_vector_type(4)));

#define NTOK 32768
#define CEMB 256
#define NHEAD 8
#define HD 32
#define BSEG 128
#define TSEG 256

// 1/sqrt(32) * log2(e): folded into Q at projection time.
#define SCQ (0.17677669529663687f * 1.4426950408889634f)

static __device__ __forceinline__ bf16x8 ld16(const u16* p) {
  uint4 v = *reinterpret_cast<const uint4*>(p);
  return __builtin_bit_cast(bf16x8, v);
}
static __device__ __forceinline__ u16 f2b(float f) {
  return __builtin_bit_cast(u16, (bf16_t)f);
}
static __device__ __forceinline__ uint4 cvt8(float4 a, float4 b) {
  u16 o[8] = {f2b(a.x), f2b(a.y), f2b(a.z), f2b(a.w),
              f2b(b.x), f2b(b.y), f2b(b.z), f2b(b.w)};
  return *reinterpret_cast<const uint4*>(o);
}

typedef __attribute__((address_space(1))) const void GASV;
typedef __attribute__((address_space(3))) void LASV;
static __device__ __forceinline__ void stage16(const u16* g, u16* l) {
  __builtin_amdgcn_global_load_lds((GASV*)g, (LASV*)l, 16, 0, 0);
}

// ---------------- K1: fused convert + QKV projection ----------------
// One block per m-tile (grid 256, 1 blk/CU). 1024 threads = 16 waves
// (4m x 4n over the 128x256 tile; wave tile 32x64).
// LDS (128 KB): [0,64K) A bf16 [128 rows][512B] XOR-swizzled, staged ONCE
// from f32 x (reg-staged cvt); [64K,96K) B bf16 [256 n][128B] swizzled,
// single-buffered, reg-staged from f32 W with load-early/write-late split;
// [96K,128K) bounce for coalesced epilogues.
__global__ __launch_bounds__(1024, 4)
void k_qkv(const float* __restrict__ x,
           const float* __restrict__ Wq, const float* __restrict__ Wk,
           const float* __restrict__ Wv,
           const float* __restrict__ bq, const float* __restrict__ bk,
           const float* __restrict__ bv,
           u16* __restrict__ q_ws, u16* __restrict__ k_ws, u16* __restrict__ v_ws) {
  const int d = blockIdx.x;
  const int m_idx = (d & 7) * 32 + (d >> 3);
  const int m0 = m_idx * 128;
  const int tid = threadIdx.x;
  const int w = tid >> 6, l = tid & 63;
  const int lr = l & 15, lg = l >> 4;
  const int wrP = w >> 2, wcP = w & 3;

  extern __shared__ char lds[];
  char* Bs = lds + 65536;
  char* bounce = lds + 98304;

  // ---- B reg-stage helpers (row = tid>>2 in 0..255, two 16B chunks) ----
  const int brow = tid >> 2;
  const int bcb = (tid & 3) * 2;
  float4 breg[2][4];
  auto BLOAD = [&](int bi, float4* r4) {
    const float* Wsel = (bi >> 2) == 0 ? Wq : ((bi >> 2) == 1 ? Wk : Wv);
    const float* s = Wsel + (size_t)brow * CEMB + (bi & 3) * 64 + bcb * 8;
    r4[0] = reinterpret_cast<const float4*>(s)[0];
    r4[1] = reinterpret_cast<const float4*>(s)[1];
    r4[2] = reinterpret_cast<const float4*>(s)[2];
    r4[3] = reinterpret_cast<const float4*>(s)[3];
  };
  auto BWRITE = [&](const float4* r4) {
#pragma unroll
    for (int jj = 0; jj < 2; ++jj) {
      int byte = brow * 128 + (((bcb + jj) * 16) ^ ((brow & 7) << 4));
      *reinterpret_cast<uint4*>(Bs + byte) = cvt8(r4[jj * 2], r4[jj * 2 + 1]);
    }
  };

  // ---- prologue: issue B(0) loads, stage A (f32 -> bf16, swizzled) ----
  BLOAD(0, breg[0]);
  {
    int row = tid >> 3, seg = tid & 7;
    const float* src = x + (size_t)(m0 + row) * CEMB + seg * 32;
#pragma unroll
    for (int j = 0; j < 4; ++j) {
      float4 a = reinterpret_cast<const float4*>(src)[2 * j];
      float4 b = reinterpret_cast<const float4*>(src)[2 * j + 1];
      int byte = row * 512 + ((seg * 64 + j * 16) ^ ((row & 7) << 4));
      *reinterpret_cast<uint4*>(lds + byte) = cvt8(a, b);
    }
  }
  BWRITE(breg[0]);
  BLOAD(1, breg[1]);
  __syncthreads();

#pragma unroll
  for (int mode = 0; mode < 3; ++mode) {
    f32x4 acc[2][4];
#pragma unroll
    for (int mf = 0; mf < 2; ++mf)
#pragma unroll
      for (int nf = 0; nf < 4; ++nf) {
        f32x4 z = {0.f, 0.f, 0.f, 0.f};
        acc[mf][nf] = z;
      }

#pragma unroll
    for (int kt = 0; kt < 4; ++kt) {
      const int bi = mode * 4 + kt;
      // compute (A persistent, B in Bs)
      bf16x8 av[2][2], bw[4][2];
#pragma unroll
      for (int mf = 0; mf < 2; ++mf)
#pragma unroll
        for (int kk = 0; kk < 2; ++kk) {
          int row = wrP * 32 + mf * 16 + lr;
          int byte = row * 512 + ((kt * 128 + kk * 64 + lg * 16) ^ ((row & 7) << 4));
          av[mf][kk] = *reinterpret_cast<const bf16x8*>(lds + byte);
        }
#pragma unroll
      for (int nf = 0; nf < 4; ++nf)
#pragma unroll
        for (int kk = 0; kk < 2; ++kk) {
          int row = wcP * 64 + nf * 16 + lr;
          int byte = row * 128 + ((kk * 64 + lg * 16) ^ ((row & 7) << 4));
          bw[nf][kk] = *reinterpret_cast<const bf16x8*>(Bs + byte);
        }
#pragma unroll
      for (int kk = 0; kk < 2; ++kk)
#pragma unroll
        for (int nf = 0; nf < 4; ++nf)
#pragma unroll
          for (int mf = 0; mf < 2; ++mf)
            acc[mf][nf] = __builtin_amdgcn_mfma_f32_16x16x32_bf16(
                av[mf][kk], bw[nf][kk], acc[mf][nf], 0, 0, 0);
      __syncthreads();  // B(bi) consumed by all waves
      if (bi < 11) {
        BWRITE(breg[(bi + 1) & 1]);
        if (bi < 10) BLOAD(bi + 2, breg[bi & 1]);
        __syncthreads();  // B(bi+1) visible
      }
    }

    // ---- epilogue for this mode ----
    const float* bias = (mode == 0) ? bq : ((mode == 1) ? bk : bv);
    float bb[4];
#pragma unroll
    for (int nf = 0; nf < 4; ++nf) bb[nf] = bias[wcP * 64 + nf * 16 + lr];

    if (mode < 2) {
      const float osc = (mode == 0) ? SCQ : 1.0f;
      u16* outp = (mode == 0) ? q_ws : k_ws;
#pragma unroll
      for (int g = 0; g < 2; ++g) {
        if ((wrP >> 1) == g) {
#pragma unroll
          for (int mf = 0; mf < 2; ++mf)
#pragma unroll
            for (int nf = 0; nf < 4; ++nf)
#pragma unroll
              for (int r = 0; r < 4; ++r) {
                int lrow = (wrP & 1) * 32 + mf * 16 + lg * 4 + r;
                int col = wcP * 64 + nf * 16 + lr;
                int byte = lrow * 512 + ((col * 2) ^ ((lrow & 7) << 4));
                *(u16*)(bounce + byte) = f2b((acc[mf][nf][r] + bb[nf]) * osc);
              }
        }
        __syncthreads();
#pragma unroll
        for (int jj = 0; jj < 2; ++jj) {
          int ch = tid * 2 + jj;
          int crow = ch >> 5, cc = ch & 31;
          int byte = crow * 512 + ((cc * 16) ^ ((crow & 7) << 4));
          *reinterpret_cast<uint4*>(outp + (size_t)(m0 + g * 64 + crow) * CEMB + cc * 8) =
              *reinterpret_cast<const uint4*>(bounce + byte);
        }
        __syncthreads();
      }
    } else {
      const int bs = m0 >> 8, t0 = m0 & 255;
#pragma unroll
      for (int g = 0; g < 2; ++g) {
        if ((wcP >> 1) == g) {
#pragma unroll
          for (int mf = 0; mf < 2; ++mf)
#pragma unroll
            for (int nf = 0; nf < 4; ++nf)
#pragma unroll
              for (int r = 0; r < 4; ++r) {
                int row = wrP * 32 + mf * 16 + lg * 4 + r;
                int ccol = (wcP & 1) * 64 + nf * 16 + lr;
                int byte = ccol * 256 + ((row * 2) ^ ((ccol & 7) << 4));
                *(u16*)(bounce + byte) = f2b(acc[mf][nf][r] + bb[nf]);
              }
        }
        __syncthreads();
#pragma unroll
        for (int jj = 0; jj < 2; ++jj) {
          int ch = tid * 2 + jj;
          int ccl = ch >> 4, cc = ch & 15;
          int byte = ccl * 256 + ((cc * 16) ^ ((ccl & 7) << 4));
          int c = g * 128 + ccl, hh = c >> 5, dd = c & 31;
          *reinterpret_cast<uint4*>(
              v_ws + ((size_t)(bs * NHEAD + hh) * HD + dd) * TSEG + t0 + cc * 8) =
              *reinterpret_cast<const uint4*>(bounce + byte);
        }
        __syncthreads();
      }
    }
  }
}

// ---------------- K2: attention + fused output projection ----------------
// R13 structure; Wp now f32, reg-staged (load-early / write-late, mean
// epilogue covers kt=0 load latency).
__global__ __launch_bounds__(1024, 4)
void k_attn(const u16* __restrict__ q_ws, const u16* __restrict__ k_ws,
            const u16* __restrict__ v_ws, const float* __restrict__ Wp,
            const float* __restrict__ bp,
            float* __restrict__ out, float* __restrict__ mean_out) {
  const int dblk = blockIdx.x;
  const int xcd = dblk & 7, ii = dblk >> 3;  // ii in 0..31
  const int b = xcd * 16 + (ii >> 1);
  const int th = ii & 1;
  const int tid = threadIdx.x;
  const int w = tid >> 6, l = tid & 63;
  const int lr = l & 15, lg = l >> 4;
  const int wt = w & 7, sh = w >> 3;
  const int tbase = th * 128 + wt * 16;

  extern __shared__ u16 ldsKV[];
  float* smb = reinterpret_cast<float*>(ldsKV + 32768);
  float* ylds = reinterpret_cast<float*>(ldsKV + 33280);
  char* yTile = reinterpret_cast<char*>(ldsKV) + 83968;

  float macc[8][4];
#pragma unroll
  for (int st = 0; st < 8; ++st)
#pragma unroll
    for (int r = 0; r < 4; ++r) macc[st][r] = 0.f;

  const u16* qseg = q_ws + (size_t)b * TSEG * CEMB;
  const u16* kseg = k_ws + (size_t)b * TSEG * CEMB;
  const u16* vseg = v_ws + (size_t)(b * NHEAD) * HD * TSEG;

  auto STAGE_KV = [&](int hn, int bn) {
    int idx = tid;                       // 0..1023 chunk id
    int c = idx >> 6, l2 = idx & 63;     // frag, lane
    int lr2 = l2 & 15, lg2 = l2 >> 4;
    int srow = 32 * (c >> 1) + 4 * (c & 1) + 8 * (lr2 >> 2) + (lr2 & 3);
    stage16(kseg + srow * CEMB + hn * HD + lg2 * 8, ldsKV + (bn * 1024 + idx) * 8);
    int vrow = (c >> 3) * 16 + lr2;
    int vcol = (c & 7) * 32 + lg2 * 8;
    stage16(vseg + (size_t)(hn * HD + vrow) * TSEG + vcol,
            ldsKV + 16384 + (bn * 1024 + idx) * 8);
  };

  STAGE_KV(0, 0);
  bf16x8 qf = ld16(qseg + (tbase + lr) * CEMB + lg * 8);

  const int own_slot = wt * 2 + sh;
  const int par_slot = wt * 2 + (1 - sh);

  for (int h = 0; h < NHEAD; ++h) {
    const int bn = h & 1;
    __syncthreads();  // B1: vmcnt drain (stage h + qf) + barrier
    if (h < 7) STAGE_KV(h + 1, bn ^ 1);
    const u16* Kb = ldsKV + bn * 8192;
    const u16* Vb = ldsKV + 16384 + bn * 8192;

    float s[8][4];
#pragma unroll
    for (int st = 0; st < 8; ++st) {
      bf16x8 kf = *reinterpret_cast<const bf16x8*>(Kb + ((sh * 8 + st) * 64 + l) * 8);
      f32x4 z = {0.f, 0.f, 0.f, 0.f};
      f32x4 dd = __builtin_amdgcn_mfma_f32_16x16x32_bf16(kf, qf, z, 0, 0, 0);
#pragma unroll
      for (int r = 0; r < 4; ++r) s[st][r] = dd[r];
    }

    qf = ld16(qseg + (tbase + lr) * CEMB + ((h + 1) & 7) * HD + lg * 8);

    float s0 = 0.f, s1 = 0.f, s2 = 0.f, s3 = 0.f;
#pragma unroll
    for (int st = 0; st < 8; ++st) {
      float p0 = exp2f(s[st][0]);
      float p1 = exp2f(s[st][1]);
      float p2 = exp2f(s[st][2]);
      float p3 = exp2f(s[st][3]);
      s[st][0] = p0; s[st][1] = p1; s[st][2] = p2; s[st][3] = p3;
      s0 += p0; s1 += p1; s2 += p2; s3 += p3;
    }
    float sm = (s0 + s1) + (s2 + s3);
    sm += __shfl_xor(sm, 16, 64);
    sm += __shfl_xor(sm, 32, 64);

    bf16x8 pb[4];
#pragma unroll
    for (int kk = 0; kk < 4; ++kk)
#pragma unroll
      for (int e = 0; e < 4; ++e) {
        pb[kk][e] = (bf16_t)s[2 * kk][e];
        pb[kk][4 + e] = (bf16_t)s[2 * kk + 1][e];
      }

    f32x4 y0 = {0.f, 0.f, 0.f, 0.f}, y1 = {0.f, 0.f, 0.f, 0.f};
#pragma unroll
    for (int kk = 0; kk < 4; ++kk) {
      bf16x8 vf0 = *reinterpret_cast<const bf16x8*>(Vb + ((0 * 8 + sh * 4 + kk) * 64 + l) * 8);
      bf16x8 vf1 = *reinterpret_cast<const bf16x8*>(Vb + ((1 * 8 + sh * 4 + kk) * 64 + l) * 8);
      y0 = __builtin_amdgcn_mfma_f32_16x16x32_bf16(vf0, pb[kk], y0, 0, 0, 0);
      y1 = __builtin_amdgcn_mfma_f32_16x16x32_bf16(vf1, pb[kk], y1, 0, 0, 0);
    }

    if (l < 16) smb[own_slot * 16 + l] = sm;
    {
      f32x4 ywr = (sh == 0) ? y1 : y0;
      *reinterpret_cast<f32x4*>(ylds + own_slot * 272 + lg * 68 + lr * 4) = ywr;
    }

    // B2: lgkm-only barrier — stage(h+1) gloads stay in flight
    __builtin_amdgcn_sched_barrier(0);
    asm volatile("s_waitcnt lgkmcnt(0)" ::: "memory");
    __builtin_amdgcn_s_barrier();
    __builtin_amdgcn_sched_barrier(0);

    float smT = sm + smb[par_slot * 16 + lr];
    float inv = __builtin_amdgcn_rcpf(smT);

#pragma unroll
    for (int st = 0; st < 8; ++st)
#pragma unroll
      for (int r = 0; r < 4; ++r)
        macc[st][r] = fmaf(s[st][r], inv, macc[st][r]);

    {
      f32x4 ymine = (sh == 0) ? y0 : y1;
      f32x4 ypar = *reinterpret_cast<const f32x4*>(ylds + par_slot * 272 + lg * 68 + lr * 4);
      u16 o[4];
#pragma unroll
      for (int r = 0; r < 4; ++r) o[r] = f2b((ymine[r] + ypar[r]) * inv);
      int row = wt * 16 + lr;
      int colb = h * 64 + sh * 32 + lg * 8;
      *reinterpret_cast<uint2*>(yTile + row * 512 + (colb ^ ((row & 7) << 4))) =
          *reinterpret_cast<const uint2*>(o);
    }
  }

  __syncthreads();  // yTile complete; KV region free

  // W reg-stage helpers (row = tid>>2 in 0..255, two 16B chunks)
  const int wrow = tid >> 2;
  const int wcb = (tid & 3) * 2;
  float4 wreg[2][4];
  auto WLOAD = [&](int kt, float4* r4) {
    const float* s = Wp + (size_t)wrow * CEMB + kt * 64 + wcb * 8;
    r4[0] = reinterpret_cast<const float4*>(s)[0];
    r4[1] = reinterpret_cast<const float4*>(s)[1];
    r4[2] = reinterpret_cast<const float4*>(s)[2];
    r4[3] = reinterpret_cast<const float4*>(s)[3];
  };
  auto WWRITE = [&](const float4* r4, int bn) {
#pragma unroll
    for (int jj = 0; jj < 2; ++jj) {
      int byte = bn * 32768 + wrow * 128 + (((wcb + jj) * 16) ^ ((wrow & 7) << 4));
      *reinterpret_cast<uint4*>(reinterpret_cast<char*>(ldsKV) + byte) =
          cvt8(r4[jj * 2], r4[jj * 2 + 1]);
    }
  };

  WLOAD(0, wreg[0]);  // latency covered by mean epilogue below

  // ---- head-mean epilogue (wave-private staging in KV region) ----
  {
    float* smem = reinterpret_cast<float*>(ldsKV);
    float* smw = smem + w * (16 * 65) + lr * 65;
    const int trow = l >> 2;
    const int cql = (l & 3) * 4;
    const float* srcp = smem + w * (16 * 65) + trow * 65 + cql;
    float* gdst = mean_out + (size_t)(b * TSEG + tbase + trow) * TSEG + sh * 128 + cql;
    for (int c = 0; c < 2; ++c) {
#pragma unroll
      for (int j = 0; j < 4; ++j) {
        int st = 4 * c + j;
        int sl = 32 * ((st >> 1) & 1) + 4 * (st & 1) + 8 * lg;
#pragma unroll
        for (int r = 0; r < 4; ++r) smw[sl + r] = macc[st][r] * 0.125f;
      }
#pragma unroll
      for (int j = 0; j < 4; ++j)
        *reinterpret_cast<f32x4*>(gdst + c * 64 + j * 16) =
            *reinterpret_cast<const f32x4*>(srcp + j * 16);
    }
  }
  __syncthreads();  // mean staging done; KV region free for W dbuf

  // ---- fused output projection: out = y * Wp^T + bp ----
  {
    const int wrP = w >> 2, wcP = w & 3;

    WWRITE(wreg[0], 0);
    WLOAD(1, wreg[1]);
    __syncthreads();

    f32x4 acc[2][4];
#pragma unroll
    for (int mf = 0; mf < 2; ++mf)
#pragma unroll
      for (int nf = 0; nf < 4; ++nf) {
        f32x4 z = {0.f, 0.f, 0.f, 0.f};
        acc[mf][nf] = z;
      }

#pragma unroll
    for (int kt = 0; kt < 4; ++kt) {
      int buf = kt & 1;
      if (kt < 3) WWRITE(wreg[(kt + 1) & 1], buf ^ 1);
      if (kt < 2) WLOAD(kt + 2, wreg[kt & 1]);
      const char* Wb = reinterpret_cast<const char*>(ldsKV) + buf * 32768;
      bf16x8 av[2][2], bw[4][2];
#pragma unroll
      for (int mf = 0; mf < 2; ++mf)
#pragma unroll
        for (int kk = 0; kk < 2; ++kk) {
          int row = wrP * 32 + mf * 16 + lr;
          int byte = row * 512 + ((kt * 128 + kk * 64 + lg * 16) ^ ((row & 7) << 4));
          av[mf][kk] = *reinterpret_cast<const bf16x8*>(yTile + byte);
        }
#pragma unroll
      for (int nf = 0; nf < 4; ++nf)
#pragma unroll
        for (int kk = 0; kk < 2; ++kk) {
          int row = wcP * 64 + nf * 16 + lr;
          int byte = row * 128 + ((kk * 64 + lg * 16) ^ ((row & 7) << 4));
          bw[nf][kk] = *reinterpret_cast<const bf16x8*>(Wb + byte);
        }
#pragma unroll
      for (int kk = 0; kk < 2; ++kk)
#pragma unroll
        for (int nf = 0; nf < 4; ++nf)
#pragma unroll
          for (int mf = 0; mf < 2; ++mf)
            acc[mf][nf] = __builtin_amdgcn_mfma_f32_16x16x32_bf16(
                av[mf][kk], bw[nf][kk], acc[mf][nf], 0, 0, 0);
      __syncthreads();
    }

    float bb[4];
#pragma unroll
    for (int nf = 0; nf < 4; ++nf) bb[nf] = bp[wcP * 64 + nf * 16 + lr];
#pragma unroll
    for (int mf = 0; mf < 2; ++mf)
#pragma unroll
      for (int nf = 0; nf < 4; ++nf)
#pragma unroll
        for (int r = 0; r < 4; ++r) {
          int m = b * TSEG + th * 128 + wrP * 32 + mf * 16 + lg * 4 + r;
          int c = wcP * 64 + nf * 16 + lr;
          out[(size_t)m * CEMB + c] = acc[mf][nf][r] + bb[nf];
        }
  }
}

extern "C" void kernel_launch(void* const* d_in, const int* in_sizes, int n_in,
                              void* d_out, int out_size, void* d_ws, size_t ws_size,
                              hipStream_t stream) {
  (void)in_sizes; (void)n_in; (void)out_size; (void)ws_size;
  const float* x  = (const float*)d_in[0];
  // d_in[1] = batch indices (unused: equal-length segments, B=128, T=256)
  const float* Wq = (const float*)d_in[2];
  const float* bq = (const float*)d_in[3];
  const float* Wk = (const float*)d_in[4];
  const float* bk = (const float*)d_in[5];
  const float* Wv = (const float*)d_in[6];
  const float* bv = (const float*)d_in[7];
  const float* Wp = (const float*)d_in[8];
  const float* bp = (const float*)d_in[9];
  float* out = (float*)d_out;

  char* ws = (char*)d_ws;
  u16* q_ws = (u16*)(ws);                    // 16 MiB, plain [m][256], pre-scaled
  u16* k_ws = (u16*)(ws + 16777216);         // 16 MiB, plain [m][256]
  u16* v_ws = (u16*)(ws + 33554432);         // 16 MiB, transposed [b,h,d,t]
  float* mean_out = out + (size_t)NTOK * CEMB;

  k_qkv<<<256, 1024, 131072, stream>>>(x, Wq, Wk, Wv, bq, bk, bv, q_ws, k_ws, v_ws);
  k_attn<<<256, 1024, 149504, stream>>>(q_ws, k_ws, v_ws, Wp, bp, out, mean_out);
}